// Round 1
// baseline (2052.600 us; speedup 1.0000x reference)
//
#include <hip/hip_runtime.h>
#include <hip/hip_cooperative_groups.h>

namespace cg = cooperative_groups;

#define NN 30000
#define NE 480000
#define BN_EPS 1e-5f
#define NBLK 7500   // NN/4 aggregate virtual blocks
#define SCB 118     // ceil(NN/256) scan blocks
#define GRID 1024   // cooperative grid: 4 blocks/CU x 256 CU
#define TB 256
#define NTH (GRID * TB)
#define BIGSTRIDE (1 << 30)

// ---------------------------------------------------------------------------
// bf16 helpers (RNE pack, cheap unpack)
// ---------------------------------------------------------------------------
__device__ __forceinline__ unsigned short f2bf(float x) {
    unsigned int u = __float_as_uint(x);
    return (unsigned short)((u + 0x7fffu + ((u >> 16) & 1u)) >> 16);
}
__device__ __forceinline__ float bf2f(unsigned short h) {
    return __uint_as_float(((unsigned int)h) << 16);
}

// int64-vs-int32 detect (see prior session notes): odd 32-bit words of an
// int64 index array with values < 2^31 are all zero.
__device__ __forceinline__ int detect64(const unsigned int* __restrict__ ei) {
    unsigned int v = ei[1] | ei[3] | ei[5] | ei[7] |
                     ei[9] | ei[11] | ei[13] | ei[15];
    return v == 0u;
}
__device__ __forceinline__ int load_idx(const void* ei, int is64, int pos) {
    if (is64) return (int)((const long long*)ei)[pos];
    return ((const int*)ei)[pos];
}

// ---------------------------------------------------------------------------
// Phase bodies shared by the cooperative mega-kernel and the fallback path.
// Each takes (start, stride) so it can be grid-strided (mega) or one-shot
// (fallback, stride = BIGSTRIDE).
// ---------------------------------------------------------------------------

// prep0: transpose W0..W2 into wt, pack U0, zero cst0; optionally zero
// degi+cursor (mega replaces the hipMemsetAsync).
__device__ __forceinline__ void dev_prep0(const float* __restrict__ W0,
                                          const float* __restrict__ W1,
                                          const float* __restrict__ W2,
                                          const float* __restrict__ U0,
                                          float* __restrict__ wt,
                                          float* __restrict__ u0pack,
                                          float* __restrict__ cst0,
                                          int* __restrict__ degi,
                                          int t0, int stride, int do_zero) {
    int limit = 3 * 16384 + 512 + (do_zero ? 2 * NN : 0);
    for (int t = t0; t < limit; t += stride) {
        if (t < 3 * 16384) {
            int layer = t >> 14;
            int r = t & 16383;
            int m = r & 3;
            int l = (r >> 2) & 63;
            int k = r >> 8;
            const float* W = (layer == 0) ? W0 : (layer == 1) ? W1 : W2;
            wt[t] = W[(m * 64 + l) * 64 + k];
        } else if (t < 3 * 16384 + 256) {
            int i = t - 3 * 16384;
            u0pack[i] = U0[(i & 3) * 64 + (i >> 2)];
        } else if (t < 3 * 16384 + 512) {
            cst0[t - 3 * 16384 - 256] = 0.0f;
        } else {
            degi[t - (3 * 16384 + 512)] = 0;  // degi + cursor contiguous
        }
    }
}

__device__ __forceinline__ void dev_hist(const void* __restrict__ ei, int is64,
                                         int* __restrict__ degi, int e0, int stride) {
    for (int e = e0; e < NE; e += stride) {
        int d = load_idx(ei, is64, NE + e);
        atomicAdd(&degi[d], 1);
    }
}

__device__ __forceinline__ void dev_scanA(const int* __restrict__ degi,
                                          int* __restrict__ bsum, int vb0, int stride) {
    __shared__ int smA[256];
    for (int vb = vb0; vb < SCB; vb += stride) {
        int t = vb * 256 + threadIdx.x;
        smA[threadIdx.x] = (t < NN) ? degi[t] : 0;
        __syncthreads();
        for (int off = 128; off > 0; off >>= 1) {
            if (threadIdx.x < off) smA[threadIdx.x] += smA[threadIdx.x + off];
            __syncthreads();
        }
        if (threadIdx.x == 0) bsum[vb] = smA[0];
        __syncthreads();
    }
}

// single-block exclusive scan of bsum -> boff (works with 256 threads)
__device__ __forceinline__ void dev_scanB(const int* __restrict__ bsum,
                                          int* __restrict__ boff) {
    __shared__ int smB[128];
    int t = threadIdx.x;
    int v = (t < SCB) ? bsum[t] : 0;
    if (t < 128) smB[t] = v;
    __syncthreads();
    for (int off = 1; off < 128; off <<= 1) {
        int add = (t >= off && t < 128) ? smB[t - off] : 0;
        __syncthreads();
        if (t < 128) smB[t] += add;
        __syncthreads();
    }
    if (t < SCB) boff[t] = smB[t] - v;  // exclusive
}

__device__ __forceinline__ void dev_scanC(const int* __restrict__ degi,
                                          const int* __restrict__ boff,
                                          int* __restrict__ rowptr, int vb0, int stride) {
    __shared__ int smC[256];
    for (int vb = vb0; vb < SCB; vb += stride) {
        int t = vb * 256 + threadIdx.x;
        int d = (t < NN) ? degi[t] : 0;
        smC[threadIdx.x] = d;
        __syncthreads();
        for (int off = 1; off < 256; off <<= 1) {
            int add = (threadIdx.x >= off) ? smC[threadIdx.x - off] : 0;
            __syncthreads();
            smC[threadIdx.x] += add;
            __syncthreads();
        }
        if (t < NN) rowptr[t] = boff[vb] + smC[threadIdx.x] - d;  // exclusive
        __syncthreads();
    }
}

__device__ __forceinline__ void dev_scatter(const void* __restrict__ ei, int is64,
                                            const int* __restrict__ rowptr,
                                            int* __restrict__ cursor,
                                            int* __restrict__ csr, int e) {
    int s = load_idx(ei, is64, e);
    int d = load_idx(ei, is64, NE + e);
    int pos = rowptr[d] + atomicAdd(&cursor[d], 1);
    csr[pos] = s;
}

// ---------------------------------------------------------------------------
// Node transform: y2[n][o] = bf16x4 of h@wtT (+cst). Wave per 4 nodes.
// Tail (threads 0..63): p for the block's 16 nodes.
// ---------------------------------------------------------------------------
__device__ __forceinline__ void dev_transform(const float* __restrict__ h,
                                              const float4* __restrict__ wt4,
                                              const float* __restrict__ cst,
                                              const float* __restrict__ usc,
                                              ushort4* __restrict__ y2,
                                              float* __restrict__ pout, int vb) {
    int lane = threadIdx.x & 63;
    int n0 = (vb * 4 + (threadIdx.x >> 6)) * 4;
    const float4* h4 = reinterpret_cast<const float4*>(h);

    float acc[4][4];
#pragma unroll
    for (int j = 0; j < 4; ++j)
#pragma unroll
        for (int m = 0; m < 4; ++m) acc[j][m] = 0.0f;

#pragma unroll 4
    for (int kb = 0; kb < 16; ++kb) {
        float hb[4][4];
#pragma unroll
        for (int j = 0; j < 4; ++j) {
            float4 v = h4[(size_t)(n0 + j) * 16 + kb];
            hb[j][0] = v.x; hb[j][1] = v.y; hb[j][2] = v.z; hb[j][3] = v.w;
        }
#pragma unroll
        for (int kk = 0; kk < 4; ++kk) {
            float4 wv = wt4[(size_t)(kb * 4 + kk) * 64 + lane];
#pragma unroll
            for (int j = 0; j < 4; ++j) {
                acc[j][0] += hb[j][kk] * wv.x;
                acc[j][1] += hb[j][kk] * wv.y;
                acc[j][2] += hb[j][kk] * wv.z;
                acc[j][3] += hb[j][kk] * wv.w;
            }
        }
    }
    float c0 = cst[lane];
    float c1 = cst[64 + lane];
    float c2 = cst[128 + lane];
    float c3 = cst[192 + lane];
#pragma unroll
    for (int j = 0; j < 4; ++j) {
        ushort4 o;
        o.x = f2bf(acc[j][0] + c0);
        o.y = f2bf(acc[j][1] + c1);
        o.z = f2bf(acc[j][2] + c2);
        o.w = f2bf(acc[j][3] + c3);
        y2[(size_t)(n0 + j) * 64 + lane] = o;
    }

    if (threadIdx.x < 64) {
        int n = vb * 16 + (threadIdx.x >> 2);
        int m = threadIdx.x & 3;
        const float4* hn = h4 + (size_t)n * 16;
        float a = 0.0f;
#pragma unroll
        for (int j = 0; j < 16; ++j) {
            float4 hv = hn[j];
            a += hv.x * usc[(4 * j + 0) * 4 + m] + hv.y * usc[(4 * j + 1) * 4 + m] +
                 hv.z * usc[(4 * j + 2) * 4 + m] + hv.w * usc[(4 * j + 3) * 4 + m];
        }
        pout[n * 4 + m] = a;
    }
}

// ---------------------------------------------------------------------------
// Fused aggregate: one wave per dst node, lane = output channel.
// ---------------------------------------------------------------------------
template <int DO_RELU_STATS>
__device__ __forceinline__ void dev_aggregate(const int* __restrict__ rowptr,
                                              const int* __restrict__ csr,
                                              const float* __restrict__ p,
                                              const ushort4* __restrict__ y2,
                                              const float* __restrict__ cvec,
                                              const float* __restrict__ bvec,
                                              float* __restrict__ hout,
                                              float* __restrict__ partial,
                                              int vb0, int vbstride) {
    __shared__ float4 attn_s[4][64];
    __shared__ int src_s[4][64];
    int wid = threadIdx.x >> 6;
    int lane = threadIdx.x & 63;
    const float4* p4 = reinterpret_cast<const float4*>(p);

    float4 cv = make_float4(cvec[0], cvec[1], cvec[2], cvec[3]);
    // self-loop attention = softmax(c), node-independent (hoisted)
    float smx = fmaxf(fmaxf(cv.x, cv.y), fmaxf(cv.z, cv.w));
    float se0 = __expf(cv.x - smx), se1 = __expf(cv.y - smx);
    float se2 = __expf(cv.z - smx), se3 = __expf(cv.w - smx);
    float sinv = 1.0f / (se0 + se1 + se2 + se3);
    float bv = bvec[lane];

    for (int vb = vb0; vb < NBLK; vb += vbstride) {
        int n = vb * 4 + wid;
        float4 pd = p4[n];
        float4 pdc = make_float4(pd.x + cv.x, pd.y + cv.y, pd.z + cv.z, pd.w + cv.w);
        ushort4 ws = y2[(unsigned)(n * 64 + lane)];
        float acc0 = (se0 * bf2f(ws.x) + se1 * bf2f(ws.y) +
                      se2 * bf2f(ws.z) + se3 * bf2f(ws.w)) * sinv;
        float acc1 = 0.0f, acc2 = 0.0f, acc3 = 0.0f;

        int start = rowptr[n];
        int end = rowptr[n + 1];
        for (int j = start; j < end; j += 64) {
            int chunk = end - j;
            if (chunk > 64) chunk = 64;
            if (lane < chunk) {
                int s = csr[j + lane];
                float4 q = p4[(unsigned)s];
                float l0 = pdc.x - q.x;
                float l1 = pdc.y - q.y;
                float l2 = pdc.z - q.z;
                float l3 = pdc.w - q.w;
                float mx = fmaxf(fmaxf(l0, l1), fmaxf(l2, l3));  // REQUIRED (R5 NaN)
                float e0 = __expf(l0 - mx);
                float e1 = __expf(l1 - mx);
                float e2 = __expf(l2 - mx);
                float e3 = __expf(l3 - mx);
                float inv = 1.0f / (e0 + e1 + e2 + e3);
                attn_s[wid][lane] = make_float4(e0 * inv, e1 * inv, e2 * inv, e3 * inv);
                src_s[wid][lane] = s;
            }
            int k = 0;
            for (; k + 4 <= chunk; k += 4) {
                float4 a0 = attn_s[wid][k];
                int s0 = src_s[wid][k];
                float4 a1 = attn_s[wid][k + 1];
                int s1 = src_s[wid][k + 1];
                float4 a2 = attn_s[wid][k + 2];
                int s2 = src_s[wid][k + 2];
                float4 a3 = attn_s[wid][k + 3];
                int s3 = src_s[wid][k + 3];
                ushort4 w0 = y2[(unsigned)(s0 * 64 + lane)];
                ushort4 w1 = y2[(unsigned)(s1 * 64 + lane)];
                ushort4 w2 = y2[(unsigned)(s2 * 64 + lane)];
                ushort4 w3 = y2[(unsigned)(s3 * 64 + lane)];
                acc0 += a0.x * bf2f(w0.x) + a0.y * bf2f(w0.y) +
                        a0.z * bf2f(w0.z) + a0.w * bf2f(w0.w);
                acc1 += a1.x * bf2f(w1.x) + a1.y * bf2f(w1.y) +
                        a1.z * bf2f(w1.z) + a1.w * bf2f(w1.w);
                acc2 += a2.x * bf2f(w2.x) + a2.y * bf2f(w2.y) +
                        a2.z * bf2f(w2.z) + a2.w * bf2f(w2.w);
                acc3 += a3.x * bf2f(w3.x) + a3.y * bf2f(w3.y) +
                        a3.z * bf2f(w3.z) + a3.w * bf2f(w3.w);
            }
            for (; k < chunk; ++k) {
                float4 a0 = attn_s[wid][k];
                int s0 = src_s[wid][k];
                ushort4 w0 = y2[(unsigned)(s0 * 64 + lane)];
                acc0 += a0.x * bf2f(w0.x) + a0.y * bf2f(w0.y) +
                        a0.z * bf2f(w0.z) + a0.w * bf2f(w0.w);
            }
        }

        float val = ((acc0 + acc1) + (acc2 + acc3)) / (float)(end - start + 1) + bv;

        if (DO_RELU_STATS) {
            __shared__ float s1m[256];
            __shared__ float s2m[256];
            val = fmaxf(val, 0.0f);
            hout[(size_t)n * 64 + lane] = val;
            s1m[threadIdx.x] = val;
            s2m[threadIdx.x] = val * val;
            __syncthreads();
            if (threadIdx.x < 64) {
                float s = s1m[threadIdx.x] + s1m[threadIdx.x + 64] +
                          s1m[threadIdx.x + 128] + s1m[threadIdx.x + 192];
                float q = s2m[threadIdx.x] + s2m[threadIdx.x + 64] +
                          s2m[threadIdx.x + 128] + s2m[threadIdx.x + 192];
                partial[vb * 128 + threadIdx.x] = s;
                partial[vb * 128 + 64 + threadIdx.x] = q;
            }
            __syncthreads();  // protect s1m/s2m reuse on next vb iteration
        } else {
            hout[(size_t)n * 64 + lane] = val;
        }
    }
}

__device__ __forceinline__ void dev_reduce(const float* __restrict__ partial,
                                           float* __restrict__ stats, int s0, int stride) {
    __shared__ float smr[256];
    for (int slot = s0; slot < 128; slot += stride) {
        float acc = 0.0f;
        for (int j = threadIdx.x; j < NBLK; j += 256)
            acc += partial[(size_t)j * 128 + slot];
        smr[threadIdx.x] = acc;
        __syncthreads();
        for (int off = 128; off > 0; off >>= 1) {
            if (threadIdx.x < off) smr[threadIdx.x] += smr[threadIdx.x + off];
            __syncthreads();
        }
        if (threadIdx.x == 0) stats[slot] = smr[0];
        __syncthreads();
    }
}

__device__ __forceinline__ float fold_sc(const float* stats, const float* g, int k) {
    const float invN = 1.0f / (float)NN;
    float mu = stats[k] * invN;
    float var = stats[64 + k] * invN - mu * mu;
    return rsqrtf(var + BN_EPS) * g[k];
}

__device__ __forceinline__ void dev_fold(const float* __restrict__ stats,
                                         const float* __restrict__ g,
                                         const float* __restrict__ bt,
                                         const float* __restrict__ Wnext,
                                         const float* __restrict__ Unext,
                                         const float* __restrict__ wt_next,
                                         float* __restrict__ wsc,
                                         float* __restrict__ usc,
                                         float* __restrict__ cst, int t0, int stride) {
    const float invN = 1.0f / (float)NN;
    for (int t = t0; t < 16384 + 512; t += stride) {
        if (t < 16384) {
            int k = t >> 8;
            wsc[t] = wt_next[t] * fold_sc(stats, g, k);
        } else if (t < 16384 + 256) {
            int o2 = t - 16384;
            float s = 0.0f;
            for (int k = 0; k < 64; ++k) {
                float mu = stats[k] * invN;
                float sc = fold_sc(stats, g, k);
                float sh = bt[k] - mu * sc;
                s += sh * Wnext[o2 * 64 + k];
            }
            cst[o2] = s;
        } else {
            int i = t - 16384 - 256;
            usc[i] = Unext[(i & 3) * 64 + (i >> 2)] * fold_sc(stats, g, i >> 2);
        }
    }
}

// ---------------------------------------------------------------------------
// Params for the mega-kernel
// ---------------------------------------------------------------------------
struct KParams {
    const float* x; const void* ei;
    const float* W0; const float* U0; const float* c0; const float* b0;
    const float* g0; const float* bt0;
    const float* W1; const float* U1; const float* c1; const float* b1;
    const float* g1; const float* bt1;
    const float* W2; const float* U2; const float* c2; const float* b2;
    float* wt; float* wsc; float* usc; float* cst; float* u0pack; float* cst0;
    ushort4* y2; float* p; float* h1; float* h2; float* stats; float* partial;
    int* degi; int* cursor; int* rowptr; int* csr; int* bsum; int* boff;
    float* out;
};

// ---------------------------------------------------------------------------
// THE mega-kernel: whole 3-layer pipeline, one dispatch, 15 grid syncs.
// 1024 blocks x 256 thr; __launch_bounds__(256,4) guarantees 4 blocks/CU
// residency for cooperative launch (VGPR<=128, LDS ~18KB <= 40KB).
// ---------------------------------------------------------------------------
__global__ __launch_bounds__(TB, 4) void mega(KParams P) {
    cg::grid_group gg = cg::this_grid();
    const int tid = blockIdx.x * TB + threadIdx.x;
    const int is64 = detect64((const unsigned int*)P.ei);

    // P0: weight transpose/pack + zero degi/cursor (replaces memset dispatch)
    dev_prep0(P.W0, P.W1, P.W2, P.U0, P.wt, P.u0pack, P.cst0, P.degi, tid, NTH, 1);
    gg.sync();

    // P1: dst-degree histogram
    dev_hist(P.ei, is64, P.degi, tid, NTH);
    gg.sync();

    // P2..P4: CSR rowptr scan
    dev_scanA(P.degi, P.bsum, blockIdx.x, GRID);
    gg.sync();
    if (blockIdx.x == 0) dev_scanB(P.bsum, P.boff);
    gg.sync();
    dev_scanC(P.degi, P.boff, P.rowptr, blockIdx.x, GRID);
    if (tid == 0) P.rowptr[NN] = NE;
    gg.sync();

    // P5: scatter (CSR fill) CONCURRENT with layer-0 transform (independent)
    for (int vb = blockIdx.x; vb < 2 * 1875; vb += GRID) {
        if (vb < 1875) {
            dev_transform(P.x, (const float4*)P.wt, P.cst0, P.u0pack, P.y2, P.p, vb);
        } else {
            dev_scatter(P.ei, is64, P.rowptr, P.cursor, P.csr,
                        (vb - 1875) * 256 + threadIdx.x);
        }
    }
    gg.sync();

    // ---- layer 0 ----
    dev_aggregate<1>(P.rowptr, P.csr, P.p, P.y2, P.c0, P.b0, P.h1, P.partial,
                     blockIdx.x, GRID);
    gg.sync();
    dev_reduce(P.partial, P.stats, blockIdx.x, GRID);
    gg.sync();
    dev_fold(P.stats, P.g0, P.bt0, P.W1, P.U1, P.wt + 16384, P.wsc, P.usc, P.cst,
             tid, NTH);
    gg.sync();

    // ---- layer 1 ----
    for (int vb = blockIdx.x; vb < 1875; vb += GRID)
        dev_transform(P.h1, (const float4*)P.wsc, P.cst, P.usc, P.y2, P.p, vb);
    gg.sync();
    dev_aggregate<1>(P.rowptr, P.csr, P.p, P.y2, P.c1, P.b1, P.h2, P.partial,
                     blockIdx.x, GRID);
    gg.sync();
    dev_reduce(P.partial, P.stats, blockIdx.x, GRID);
    gg.sync();
    dev_fold(P.stats, P.g1, P.bt1, P.W2, P.U2, P.wt + 2 * 16384, P.wsc, P.usc, P.cst,
             tid, NTH);
    gg.sync();

    // ---- layer 2 ----
    for (int vb = blockIdx.x; vb < 1875; vb += GRID)
        dev_transform(P.h2, (const float4*)P.wsc, P.cst, P.usc, P.y2, P.p, vb);
    gg.sync();
    dev_aggregate<0>(P.rowptr, P.csr, P.p, P.y2, P.c2, P.b2, P.out, nullptr,
                     blockIdx.x, GRID);
}

// ---------------------------------------------------------------------------
// Fallback kernels (classic 18-dispatch pipeline) — used only if the
// cooperative launch is rejected. Same device bodies, one-shot strides.
// ---------------------------------------------------------------------------
__global__ __launch_bounds__(256) void k_prep0(const float* W0, const float* W1,
                                               const float* W2, const float* U0,
                                               float* wt, float* u0pack, float* cst0) {
    dev_prep0(W0, W1, W2, U0, wt, u0pack, cst0, nullptr,
              blockIdx.x * 256 + threadIdx.x, BIGSTRIDE, 0);
}
__global__ __launch_bounds__(256) void k_hist(const void* ei, int* degi) {
    int is64 = detect64((const unsigned int*)ei);
    dev_hist(ei, is64, degi, blockIdx.x * 256 + threadIdx.x, BIGSTRIDE);
}
__global__ __launch_bounds__(256) void k_scanA(const int* degi, int* bsum) {
    dev_scanA(degi, bsum, blockIdx.x, BIGSTRIDE);
}
__global__ __launch_bounds__(256) void k_scanB(const int* bsum, int* boff) {
    dev_scanB(bsum, boff);
}
__global__ __launch_bounds__(256) void k_scanC(const int* degi, const int* boff,
                                               int* rowptr) {
    dev_scanC(degi, boff, rowptr, blockIdx.x, BIGSTRIDE);
    if (blockIdx.x == 0 && threadIdx.x == 0) rowptr[NN] = NE;
}
__global__ __launch_bounds__(256) void k_scatter(const void* ei, const int* rowptr,
                                                 int* cursor, int* csr) {
    int e = blockIdx.x * 256 + threadIdx.x;
    if (e < NE) {
        int is64 = detect64((const unsigned int*)ei);
        dev_scatter(ei, is64, rowptr, cursor, csr, e);
    }
}
__global__ __launch_bounds__(256) void k_transform(const float* h, const float4* wt4,
                                                   const float* cst, const float* usc,
                                                   ushort4* y2, float* pout) {
    dev_transform(h, wt4, cst, usc, y2, pout, blockIdx.x);
}
template <int D>
__global__ __launch_bounds__(256) void k_aggregate(const int* rowptr, const int* csr,
                                                   const float* p, const ushort4* y2,
                                                   const float* cvec, const float* bvec,
                                                   float* hout, float* partial) {
    dev_aggregate<D>(rowptr, csr, p, y2, cvec, bvec, hout, partial, blockIdx.x,
                     BIGSTRIDE);
}
__global__ __launch_bounds__(256) void k_reduce(const float* partial, float* stats) {
    dev_reduce(partial, stats, blockIdx.x, BIGSTRIDE);
}
__global__ __launch_bounds__(256) void k_fold(const float* stats, const float* g,
                                              const float* bt, const float* Wn,
                                              const float* Un, const float* wtn,
                                              float* wsc, float* usc, float* cst) {
    dev_fold(stats, g, bt, Wn, Un, wtn, wsc, usc, cst,
             blockIdx.x * 256 + threadIdx.x, BIGSTRIDE);
}

extern "C" void kernel_launch(void* const* d_in, const int* in_sizes, int n_in,
                              void* d_out, int out_size, void* d_ws, size_t ws_size,
                              hipStream_t stream) {
    const float* x = (const float*)d_in[0];
    const void* ei = d_in[1];
    const float* W0 = (const float*)d_in[2];
    const float* U0 = (const float*)d_in[3];
    const float* c0 = (const float*)d_in[4];
    const float* b0 = (const float*)d_in[5];
    const float* g0 = (const float*)d_in[6];
    const float* bt0 = (const float*)d_in[7];
    const float* W1 = (const float*)d_in[8];
    const float* U1 = (const float*)d_in[9];
    const float* c1 = (const float*)d_in[10];
    const float* b1 = (const float*)d_in[11];
    const float* g1 = (const float*)d_in[12];
    const float* bt1 = (const float*)d_in[13];
    const float* W2 = (const float*)d_in[14];
    const float* U2 = (const float*)d_in[15];
    const float* c2 = (const float*)d_in[16];
    const float* b2 = (const float*)d_in[17];

    float* ws = (float*)d_ws;
    float* wt = ws;                          // 3*16384
    float* wsc = wt + 3 * 16384;             // 16384
    float* usc = wsc + 16384;                // 256
    float* cst = usc + 256;                  // 256
    float* u0pack = cst + 256;               // 256
    float* cst0 = u0pack + 256;              // 256
    ushort4* y2 = (ushort4*)(cst0 + 256);    // NN*64 ushort4 (15.36 MB)
    float* p = (float*)((unsigned short*)y2 + (size_t)NN * 256);  // NN*4
    float* h1 = p + (size_t)NN * 4;          // NN*64
    float* h2 = h1 + (size_t)NN * 64;        // NN*64
    float* stats = h2 + (size_t)NN * 64;     // 128
    float* partial = stats + 128;            // NBLK*128
    int* degi = (int*)(partial + (size_t)NBLK * 128);  // NN
    int* cursor = degi + NN;                 // NN (contiguous: single zero pass)
    int* rowptr = cursor + NN;               // NN+1
    int* csr = rowptr + NN + 1;              // NE
    int* bsum = csr + NE;                    // SCB
    int* boff = bsum + SCB;                  // SCB

    KParams P;
    P.x = x; P.ei = ei;
    P.W0 = W0; P.U0 = U0; P.c0 = c0; P.b0 = b0; P.g0 = g0; P.bt0 = bt0;
    P.W1 = W1; P.U1 = U1; P.c1 = c1; P.b1 = b1; P.g1 = g1; P.bt1 = bt1;
    P.W2 = W2; P.U2 = U2; P.c2 = c2; P.b2 = b2;
    P.wt = wt; P.wsc = wsc; P.usc = usc; P.cst = cst; P.u0pack = u0pack;
    P.cst0 = cst0; P.y2 = y2; P.p = p; P.h1 = h1; P.h2 = h2;
    P.stats = stats; P.partial = partial;
    P.degi = degi; P.cursor = cursor; P.rowptr = rowptr; P.csr = csr;
    P.bsum = bsum; P.boff = boff;
    P.out = (float*)d_out;

    void* args[] = {(void*)&P};
    hipError_t err = hipLaunchCooperativeKernel((void*)mega, dim3(GRID), dim3(TB),
                                                args, 0, stream);
    if (err != hipSuccess) {
        // Fallback: classic pipeline (known-good 394 us path)
        (void)hipGetLastError();
        const int TBl = 256;
        const int tfBlocks = 1875;
        const int aggBlocks = NBLK;
        const int eBlocks = NE / TBl;
        const int trBlocks = (3 * 16384 + 512 + TBl - 1) / TBl;
        const int foldBlocks = (16384 + 512 + TBl - 1) / TBl;

        k_prep0<<<trBlocks, TBl, 0, stream>>>(W0, W1, W2, U0, wt, u0pack, cst0);
        hipMemsetAsync(degi, 0, sizeof(int) * 2 * NN, stream);
        k_hist<<<eBlocks, TBl, 0, stream>>>(ei, degi);
        k_scanA<<<SCB, TBl, 0, stream>>>(degi, bsum);
        k_scanB<<<1, TBl, 0, stream>>>(bsum, boff);
        k_scanC<<<SCB, TBl, 0, stream>>>(degi, boff, rowptr);
        k_scatter<<<eBlocks, TBl, 0, stream>>>(ei, rowptr, cursor, csr);

        const float4* wt4_0 = reinterpret_cast<const float4*>(wt);
        const float4* wsc4 = reinterpret_cast<const float4*>(wsc);

        k_transform<<<tfBlocks, TBl, 0, stream>>>(x, wt4_0, cst0, u0pack, y2, p);
        k_aggregate<1><<<aggBlocks, TBl, 0, stream>>>(rowptr, csr, p, y2, c0, b0, h1, partial);
        k_reduce<<<128, TBl, 0, stream>>>(partial, stats);
        k_fold<<<foldBlocks, TBl, 0, stream>>>(stats, g0, bt0, W1, U1, wt + 16384, wsc, usc, cst);

        k_transform<<<tfBlocks, TBl, 0, stream>>>(h1, wsc4, cst, usc, y2, p);
        k_aggregate<1><<<aggBlocks, TBl, 0, stream>>>(rowptr, csr, p, y2, c1, b1, h2, partial);
        k_reduce<<<128, TBl, 0, stream>>>(partial, stats);
        k_fold<<<foldBlocks, TBl, 0, stream>>>(stats, g1, bt1, W2, U2, wt + 2 * 16384, wsc, usc, cst);

        k_transform<<<tfBlocks, TBl, 0, stream>>>(h2, wsc4, cst, usc, y2, p);
        k_aggregate<0><<<aggBlocks, TBl, 0, stream>>>(rowptr, csr, p, y2, c2, b2, (float*)d_out, nullptr);
    }
}

// Round 2
// 500.649 us; speedup vs baseline: 4.0999x; 4.0999x over previous
//
#include <hip/hip_runtime.h>

#define NN 30000
#define NE 480000
#define BN_EPS 1e-5f
#define TFBLK 1875    // NN/16 transform blocks (16 nodes each)
#define EBLK 1875     // NE/256 edge blocks
#define AGGBLK 1875   // aggregate blocks, 4 virtual sub-blocks (16 nodes) each

// ---------------------------------------------------------------------------
// bf16 helpers (RNE pack, cheap unpack)
// ---------------------------------------------------------------------------
__device__ __forceinline__ unsigned short f2bf(float x) {
    unsigned int u = __float_as_uint(x);
    return (unsigned short)((u + 0x7fffu + ((u >> 16) & 1u)) >> 16);
}
__device__ __forceinline__ float bf2f(unsigned short h) {
    return __uint_as_float(((unsigned int)h) << 16);
}

// int64-vs-int32 detect: odd 32-bit words of int64 indices < 2^31 are all 0.
__device__ __forceinline__ int detect64(const unsigned int* __restrict__ ei) {
    unsigned int v = ei[1] | ei[3] | ei[5] | ei[7] |
                     ei[9] | ei[11] | ei[13] | ei[15];
    return v == 0u;
}
__device__ __forceinline__ int load_idx(const void* ei, int is64, int pos) {
    if (is64) return (int)((const long long*)ei)[pos];
    return ((const int*)ei)[pos];
}

// ---------------------------------------------------------------------------
// prep: transpose W0..W2 into wt  (wt[(k*64+l)*4+m] = W[(m*64+l)*64+k]),
// zero degi+cursor (contiguous 2*NN), zero stats01[256].
// ---------------------------------------------------------------------------
__global__ __launch_bounds__(256) void k_prep(const float* __restrict__ W0,
                                              const float* __restrict__ W1,
                                              const float* __restrict__ W2,
                                              float* __restrict__ wt,
                                              int* __restrict__ degi,
                                              float* __restrict__ stats01) {
    int t = blockIdx.x * 256 + threadIdx.x;
    if (t < 3 * 16384) {
        int layer = t >> 14;
        int r = t & 16383;
        int m = r & 3;
        int l = (r >> 2) & 63;
        int k = r >> 8;
        const float* W = (layer == 0) ? W0 : (layer == 1) ? W1 : W2;
        wt[t] = W[(m * 64 + l) * 64 + k];
    } else if (t < 3 * 16384 + 2 * NN) {
        degi[t - 3 * 16384] = 0;
    } else if (t < 3 * 16384 + 2 * NN + 256) {
        stats01[t - 3 * 16384 - 2 * NN] = 0.0f;
    }
}

// ---------------------------------------------------------------------------
// hist: dst-degree histogram (exactly NE threads: 1875 x 256)
// ---------------------------------------------------------------------------
__global__ __launch_bounds__(256) void k_hist(const void* __restrict__ ei,
                                              int* __restrict__ degi) {
    int e = blockIdx.x * 256 + threadIdx.x;
    int is64 = detect64((const unsigned int*)ei);
    int d = load_idx(ei, is64, NE + e);
    atomicAdd(&degi[d], 1);
}

// ---------------------------------------------------------------------------
// scan: ONE block, 1024 threads, 30 elems/thread -> exclusive rowptr.
// Replaces the 3-dispatch scanA/B/C chain. 240 KB traffic, trivial.
// ---------------------------------------------------------------------------
__global__ __launch_bounds__(1024) void k_scan(const int* __restrict__ degi,
                                               int* __restrict__ rowptr) {
    __shared__ int sm[1024];
    const int PER = 30;  // 1024*30 = 30720 >= NN
    int t = threadIdx.x;
    int base = t * PER;
    int loc[PER];
    int sum = 0;
#pragma unroll
    for (int i = 0; i < PER; ++i) {
        int idx = base + i;
        int d = (idx < NN) ? degi[idx] : 0;
        loc[i] = sum;  // exclusive within-thread prefix
        sum += d;
    }
    sm[t] = sum;
    __syncthreads();
    for (int off = 1; off < 1024; off <<= 1) {
        int add = (t >= off) ? sm[t - off] : 0;
        __syncthreads();
        sm[t] += add;
        __syncthreads();
    }
    int tb = sm[t] - sum;  // exclusive block prefix
#pragma unroll
    for (int i = 0; i < PER; ++i) {
        int idx = base + i;
        if (idx < NN) rowptr[idx] = tb + loc[i];
    }
    if (t == 0) rowptr[NN] = NE;
}

// ---------------------------------------------------------------------------
// Transform with optional BN-fold computed IN-KERNEL (replaces fold dispatch):
//   sc[k] = g[k]*rsqrt(var+eps), sh[k] = bt[k]-mu*sc[k]  (from stats)
//   y2 = h @ (W*sc)^T + cst,  cst[o2] = sum_k sh[k]*Wnext[o2*64+k]
//   p-tail: h @ (U*sc)^T   (sh shift cancels in logit differences)
// Wave per 4 nodes; tail threads 0..63 compute p for the block's 16 nodes.
// ---------------------------------------------------------------------------
template <int FOLD>
__device__ __forceinline__ void dev_tf(const float* __restrict__ h,
                                       const float4* __restrict__ wt4,
                                       const float* __restrict__ stats,
                                       const float* __restrict__ g,
                                       const float* __restrict__ bt,
                                       const float* __restrict__ Wnext,
                                       const float* __restrict__ Uraw,
                                       ushort4* __restrict__ y2,
                                       float* __restrict__ pout, int vb) {
    __shared__ float sc_s[64];
    __shared__ float sh_s[64];
    __shared__ float cst_s[256];
    if (FOLD) {
        if (threadIdx.x < 64) {
            int k = threadIdx.x;
            const float invN = 1.0f / (float)NN;
            float mu = stats[k] * invN;
            float var = stats[64 + k] * invN - mu * mu;
            float sc = rsqrtf(var + BN_EPS) * g[k];
            sc_s[k] = sc;
            sh_s[k] = bt[k] - mu * sc;
        }
        __syncthreads();
        {
            float s = 0.0f;
            const float* wr = Wnext + threadIdx.x * 64;
#pragma unroll 8
            for (int k = 0; k < 64; ++k) s += sh_s[k] * wr[k];
            cst_s[threadIdx.x] = s;
        }
        __syncthreads();
    }

    int lane = threadIdx.x & 63;
    int n0 = (vb * 4 + (threadIdx.x >> 6)) * 4;
    const float4* h4 = reinterpret_cast<const float4*>(h);

    float acc[4][4];
#pragma unroll
    for (int j = 0; j < 4; ++j)
#pragma unroll
        for (int m = 0; m < 4; ++m) acc[j][m] = 0.0f;

#pragma unroll 4
    for (int kb = 0; kb < 16; ++kb) {
        float hb[4][4];
#pragma unroll
        for (int j = 0; j < 4; ++j) {
            float4 v = h4[(size_t)(n0 + j) * 16 + kb];
            hb[j][0] = v.x; hb[j][1] = v.y; hb[j][2] = v.z; hb[j][3] = v.w;
        }
#pragma unroll
        for (int kk = 0; kk < 4; ++kk) {
            float4 wv = wt4[(size_t)(kb * 4 + kk) * 64 + lane];
            if (FOLD) {
                float sck = sc_s[kb * 4 + kk];
                wv.x *= sck; wv.y *= sck; wv.z *= sck; wv.w *= sck;
            }
#pragma unroll
            for (int j = 0; j < 4; ++j) {
                acc[j][0] += hb[j][kk] * wv.x;
                acc[j][1] += hb[j][kk] * wv.y;
                acc[j][2] += hb[j][kk] * wv.z;
                acc[j][3] += hb[j][kk] * wv.w;
            }
        }
    }
    float c0, c1, c2, c3;
    if (FOLD) {
        c0 = cst_s[lane];
        c1 = cst_s[64 + lane];
        c2 = cst_s[128 + lane];
        c3 = cst_s[192 + lane];
    } else {
        c0 = c1 = c2 = c3 = 0.0f;
    }
#pragma unroll
    for (int j = 0; j < 4; ++j) {
        ushort4 o;
        o.x = f2bf(acc[j][0] + c0);
        o.y = f2bf(acc[j][1] + c1);
        o.z = f2bf(acc[j][2] + c2);
        o.w = f2bf(acc[j][3] + c3);
        y2[(size_t)(n0 + j) * 64 + lane] = o;
    }

    // p tail: one (node, head) scalar per thread; block covers 16 nodes.
    if (threadIdx.x < 64) {
        int n = vb * 16 + (threadIdx.x >> 2);
        int m = threadIdx.x & 3;
        const float* Um = Uraw + m * 64;
        const float4* hn = h4 + (size_t)n * 16;
        float a = 0.0f;
#pragma unroll
        for (int j = 0; j < 16; ++j) {
            float4 hv = hn[j];
            if (FOLD) {
                a += hv.x * (Um[4 * j + 0] * sc_s[4 * j + 0]) +
                     hv.y * (Um[4 * j + 1] * sc_s[4 * j + 1]) +
                     hv.z * (Um[4 * j + 2] * sc_s[4 * j + 2]) +
                     hv.w * (Um[4 * j + 3] * sc_s[4 * j + 3]);
            } else {
                a += hv.x * Um[4 * j + 0] + hv.y * Um[4 * j + 1] +
                     hv.z * Um[4 * j + 2] + hv.w * Um[4 * j + 3];
            }
        }
        pout[n * 4 + m] = a;
    }
}

// ---------------------------------------------------------------------------
// Fused dispatch: blocks 0..1874 = layer-0 transform (no fold);
// blocks 1875..3749 = CSR scatter (independent work, saves a boundary).
// dev_tf<0> contains no __syncthreads, so divergent block roles are safe.
// ---------------------------------------------------------------------------
__global__ __launch_bounds__(256) void k_tf0_scatter(const float* __restrict__ x,
                                                     const float4* __restrict__ wt4,
                                                     const float* __restrict__ U0,
                                                     ushort4* __restrict__ y2,
                                                     float* __restrict__ p,
                                                     const void* __restrict__ ei,
                                                     const int* __restrict__ rowptr,
                                                     int* __restrict__ cursor,
                                                     int* __restrict__ csr) {
    int vb = blockIdx.x;
    if (vb < TFBLK) {
        dev_tf<0>(x, wt4, nullptr, nullptr, nullptr, nullptr, U0, y2, p, vb);
    } else {
        int is64 = detect64((const unsigned int*)ei);
        int e = (vb - TFBLK) * 256 + threadIdx.x;
        int s = load_idx(ei, is64, e);
        int d = load_idx(ei, is64, NE + e);
        int pos = rowptr[d] + atomicAdd(&cursor[d], 1);
        csr[pos] = s;
    }
}

__global__ __launch_bounds__(256) void k_tf_fold(const float* __restrict__ h,
                                                 const float4* __restrict__ wt4,
                                                 const float* __restrict__ stats,
                                                 const float* __restrict__ g,
                                                 const float* __restrict__ bt,
                                                 const float* __restrict__ Wnext,
                                                 const float* __restrict__ Unext,
                                                 ushort4* __restrict__ y2,
                                                 float* __restrict__ p) {
    dev_tf<1>(h, wt4, stats, g, bt, Wnext, Unext, y2, p, blockIdx.x);
}

// ---------------------------------------------------------------------------
// Aggregate: wave per dst node, lane = channel; 4 node-groups per block
// (16 contiguous nodes). Stats (sum, sumsq per channel) accumulate in
// registers across the 4 groups, flushed once via 128 atomicAdds
// (replaces partial buffer + reduce dispatch; order nondeterminism is
// harmless at fp32 vs the BN math).
// ---------------------------------------------------------------------------
template <int DO_STATS>
__global__ __launch_bounds__(256) void k_agg(const int* __restrict__ rowptr,
                                             const int* __restrict__ csr,
                                             const float* __restrict__ p,
                                             const ushort4* __restrict__ y2,
                                             const float* __restrict__ cvec,
                                             const float* __restrict__ bvec,
                                             float* __restrict__ hout,
                                             float* __restrict__ stats) {
    __shared__ float4 attn_s[4][64];
    __shared__ int src_s[4][64];
    int wid = threadIdx.x >> 6;
    int lane = threadIdx.x & 63;
    const float4* p4 = reinterpret_cast<const float4*>(p);

    float4 cv = make_float4(cvec[0], cvec[1], cvec[2], cvec[3]);
    // self-loop attention = softmax(c), node-independent (hoisted)
    float smx = fmaxf(fmaxf(cv.x, cv.y), fmaxf(cv.z, cv.w));
    float se0 = __expf(cv.x - smx), se1 = __expf(cv.y - smx);
    float se2 = __expf(cv.z - smx), se3 = __expf(cv.w - smx);
    float sinv = 1.0f / (se0 + se1 + se2 + se3);
    float bv = bvec[lane];
    float ls = 0.0f, lq = 0.0f;

#pragma unroll 1
    for (int r = 0; r < 4; ++r) {
        int n = (blockIdx.x * 4 + r) * 4 + wid;
        float4 pd = p4[n];
        float4 pdc = make_float4(pd.x + cv.x, pd.y + cv.y, pd.z + cv.z, pd.w + cv.w);
        ushort4 ws = y2[(unsigned)(n * 64 + lane)];
        float acc0 = (se0 * bf2f(ws.x) + se1 * bf2f(ws.y) +
                      se2 * bf2f(ws.z) + se3 * bf2f(ws.w)) * sinv;
        float acc1 = 0.0f, acc2 = 0.0f, acc3 = 0.0f;

        int start = rowptr[n];
        int end = rowptr[n + 1];
        for (int j = start; j < end; j += 64) {
            int chunk = end - j;
            if (chunk > 64) chunk = 64;
            if (lane < chunk) {
                int s = csr[j + lane];
                float4 q = p4[(unsigned)s];
                float l0 = pdc.x - q.x;
                float l1 = pdc.y - q.y;
                float l2 = pdc.z - q.z;
                float l3 = pdc.w - q.w;
                float mx = fmaxf(fmaxf(l0, l1), fmaxf(l2, l3));  // REQUIRED (R5 NaN)
                float e0 = __expf(l0 - mx);
                float e1 = __expf(l1 - mx);
                float e2 = __expf(l2 - mx);
                float e3 = __expf(l3 - mx);
                float inv = 1.0f / (e0 + e1 + e2 + e3);
                attn_s[wid][lane] = make_float4(e0 * inv, e1 * inv, e2 * inv, e3 * inv);
                src_s[wid][lane] = s;
            }
            int k = 0;
            for (; k + 4 <= chunk; k += 4) {
                float4 a0 = attn_s[wid][k];
                int s0 = src_s[wid][k];
                float4 a1 = attn_s[wid][k + 1];
                int s1 = src_s[wid][k + 1];
                float4 a2 = attn_s[wid][k + 2];
                int s2 = src_s[wid][k + 2];
                float4 a3 = attn_s[wid][k + 3];
                int s3 = src_s[wid][k + 3];
                ushort4 w0 = y2[(unsigned)(s0 * 64 + lane)];
                ushort4 w1 = y2[(unsigned)(s1 * 64 + lane)];
                ushort4 w2 = y2[(unsigned)(s2 * 64 + lane)];
                ushort4 w3 = y2[(unsigned)(s3 * 64 + lane)];
                acc0 += a0.x * bf2f(w0.x) + a0.y * bf2f(w0.y) +
                        a0.z * bf2f(w0.z) + a0.w * bf2f(w0.w);
                acc1 += a1.x * bf2f(w1.x) + a1.y * bf2f(w1.y) +
                        a1.z * bf2f(w1.z) + a1.w * bf2f(w1.w);
                acc2 += a2.x * bf2f(w2.x) + a2.y * bf2f(w2.y) +
                        a2.z * bf2f(w2.z) + a2.w * bf2f(w2.w);
                acc3 += a3.x * bf2f(w3.x) + a3.y * bf2f(w3.y) +
                        a3.z * bf2f(w3.z) + a3.w * bf2f(w3.w);
            }
            for (; k < chunk; ++k) {
                float4 a0 = attn_s[wid][k];
                int s0 = src_s[wid][k];
                ushort4 w0 = y2[(unsigned)(s0 * 64 + lane)];
                acc0 += a0.x * bf2f(w0.x) + a0.y * bf2f(w0.y) +
                        a0.z * bf2f(w0.z) + a0.w * bf2f(w0.w);
            }
        }

        float val = ((acc0 + acc1) + (acc2 + acc3)) / (float)(end - start + 1) + bv;

        if (DO_STATS) {
            val = fmaxf(val, 0.0f);
            hout[(size_t)n * 64 + lane] = val;
            ls += val;
            lq += val * val;
        } else {
            hout[(size_t)n * 64 + lane] = val;
        }
    }

    if (DO_STATS) {
        __shared__ float s1m[256];
        __shared__ float s2m[256];
        s1m[threadIdx.x] = ls;
        s2m[threadIdx.x] = lq;
        __syncthreads();
        if (threadIdx.x < 64) {
            float s = s1m[threadIdx.x] + s1m[threadIdx.x + 64] +
                      s1m[threadIdx.x + 128] + s1m[threadIdx.x + 192];
            float q = s2m[threadIdx.x] + s2m[threadIdx.x + 64] +
                      s2m[threadIdx.x + 128] + s2m[threadIdx.x + 192];
            atomicAdd(&stats[threadIdx.x], s);
            atomicAdd(&stats[64 + threadIdx.x], q);
        }
    }
}

extern "C" void kernel_launch(void* const* d_in, const int* in_sizes, int n_in,
                              void* d_out, int out_size, void* d_ws, size_t ws_size,
                              hipStream_t stream) {
    const float* x = (const float*)d_in[0];
    const void* ei = d_in[1];
    const float* W0 = (const float*)d_in[2];
    const float* U0 = (const float*)d_in[3];
    const float* c0 = (const float*)d_in[4];
    const float* b0 = (const float*)d_in[5];
    const float* g0 = (const float*)d_in[6];
    const float* bt0 = (const float*)d_in[7];
    const float* W1 = (const float*)d_in[8];
    const float* U1 = (const float*)d_in[9];
    const float* c1 = (const float*)d_in[10];
    const float* b1 = (const float*)d_in[11];
    const float* g1 = (const float*)d_in[12];
    const float* bt1 = (const float*)d_in[13];
    const float* W2 = (const float*)d_in[14];
    const float* U2 = (const float*)d_in[15];
    const float* c2 = (const float*)d_in[16];
    const float* b2 = (const float*)d_in[17];

    float* ws = (float*)d_ws;
    float* wt = ws;                                   // 3*16384
    ushort4* y2 = (ushort4*)(wt + 3 * 16384);         // NN*64 ushort4 (15.36 MB)
    float* p = (float*)((unsigned short*)y2 + (size_t)NN * 256);  // NN*4
    float* h1 = p + (size_t)NN * 4;                   // NN*64
    float* h2 = h1 + (size_t)NN * 64;                 // NN*64
    float* stats01 = h2 + (size_t)NN * 64;            // 256 (stats0, stats1)
    int* degi = (int*)(stats01 + 256);                // NN
    int* cursor = degi + NN;                          // NN (contiguous with degi)
    int* rowptr = cursor + NN;                        // NN+1
    int* csr = rowptr + NN + 1;                       // NE

    const int prepBlocks = (3 * 16384 + 2 * NN + 256 + 255) / 256;  // 428

    // 9 dispatches total (was 19): no memset, no scanA/B/C, no reduce, no fold.
    k_prep<<<prepBlocks, 256, 0, stream>>>(W0, W1, W2, wt, degi, stats01);
    k_hist<<<EBLK, 256, 0, stream>>>(ei, degi);
    k_scan<<<1, 1024, 0, stream>>>(degi, rowptr);
    k_tf0_scatter<<<2 * TFBLK, 256, 0, stream>>>(x, (const float4*)wt, U0, y2, p,
                                                 ei, rowptr, cursor, csr);

    // ---- layer 0 ----
    k_agg<1><<<AGGBLK, 256, 0, stream>>>(rowptr, csr, p, y2, c0, b0, h1, stats01);
    // ---- layer 1 (BN0 folded in-kernel from stats01[0:128]) ----
    k_tf_fold<<<TFBLK, 256, 0, stream>>>(h1, (const float4*)(wt + 16384), stats01,
                                         g0, bt0, W1, U1, y2, p);
    k_agg<1><<<AGGBLK, 256, 0, stream>>>(rowptr, csr, p, y2, c1, b1, h2,
                                         stats01 + 128);
    // ---- layer 2 (BN1 folded in-kernel from stats01[128:256]) ----
    k_tf_fold<<<TFBLK, 256, 0, stream>>>(h2, (const float4*)(wt + 2 * 16384),
                                         stats01 + 128, g1, bt1, W2, U2, y2, p);
    k_agg<0><<<AGGBLK, 256, 0, stream>>>(rowptr, csr, p, y2, c2, b2,
                                         (float*)d_out, nullptr);
}

// Round 3
// 462.035 us; speedup vs baseline: 4.4425x; 1.0836x over previous
//
#include <hip/hip_runtime.h>

#define NN 30000
#define NE 480000
#define BN_EPS 1e-5f
#define EBLK 1875     // NE/256 edge blocks
#define AGGBLK 7500   // wave per node
#define POSTBLK 1875  // 16 nodes per block
#define PKBLK 469     // ceil(NN*4/256)

// ---------------------------------------------------------------------------
// bf16 helpers (RNE pack, cheap unpack)
// ---------------------------------------------------------------------------
__device__ __forceinline__ unsigned short f2bf(float x) {
    unsigned int u = __float_as_uint(x);
    return (unsigned short)((u + 0x7fffu + ((u >> 16) & 1u)) >> 16);
}
__device__ __forceinline__ float bf2f(unsigned short h) {
    return __uint_as_float(((unsigned int)h) << 16);
}

// int64-vs-int32 detect: odd 32-bit words of int64 indices < 2^31 are all 0.
__device__ __forceinline__ int detect64(const unsigned int* __restrict__ ei) {
    unsigned int v = ei[1] | ei[3] | ei[5] | ei[7] |
                     ei[9] | ei[11] | ei[13] | ei[15];
    return v == 0u;
}
__device__ __forceinline__ int load_idx(const void* ei, int is64, int pos) {
    if (is64) return (int)((const long long*)ei)[pos];
    return ((const int*)ei)[pos];
}

// ---------------------------------------------------------------------------
// prep: x -> xbf (bf16), zero degi+cursor+stats (contiguous int4 region).
// No weight transpose anymore: post reads W in native [256][64] layout.
// ---------------------------------------------------------------------------
__global__ __launch_bounds__(256) void k_prep(const float* __restrict__ x,
                                              ushort* __restrict__ xbf,
                                              int4* __restrict__ zerobase) {
    int t = blockIdx.x * 256 + threadIdx.x;
    if (t < 480000) {  // NN*64/4 float4s
        float4 v = reinterpret_cast<const float4*>(x)[t];
        ushort4 o;
        o.x = f2bf(v.x); o.y = f2bf(v.y); o.z = f2bf(v.z); o.w = f2bf(v.w);
        reinterpret_cast<ushort4*>(xbf)[t] = o;
    } else if (t < 480000 + 15064) {  // (2*NN ints + 256 floats)/4
        zerobase[t - 480000] = make_int4(0, 0, 0, 0);
    }
}

// ---------------------------------------------------------------------------
// hist: dst-degree histogram (exactly NE threads)
// ---------------------------------------------------------------------------
__global__ __launch_bounds__(256) void k_hist(const void* __restrict__ ei,
                                              int* __restrict__ degi) {
    int e = blockIdx.x * 256 + threadIdx.x;
    int is64 = detect64((const unsigned int*)ei);
    int d = load_idx(ei, is64, NE + e);
    atomicAdd(&degi[d], 1);
}

// ---------------------------------------------------------------------------
// scan: ONE block, 1024 threads, 30 elems/thread -> exclusive rowptr.
// ---------------------------------------------------------------------------
__global__ __launch_bounds__(1024) void k_scan(const int* __restrict__ degi,
                                               int* __restrict__ rowptr) {
    __shared__ int sm[1024];
    const int PER = 30;
    int t = threadIdx.x;
    int base = t * PER;
    int loc[PER];
    int sum = 0;
#pragma unroll
    for (int i = 0; i < PER; ++i) {
        int idx = base + i;
        int d = (idx < NN) ? degi[idx] : 0;
        loc[i] = sum;
        sum += d;
    }
    sm[t] = sum;
    __syncthreads();
    for (int off = 1; off < 1024; off <<= 1) {
        int add = (t >= off) ? sm[t - off] : 0;
        __syncthreads();
        sm[t] += add;
        __syncthreads();
    }
    int tb = sm[t] - sum;
#pragma unroll
    for (int i = 0; i < PER; ++i) {
        int idx = base + i;
        if (idx < NN) rowptr[idx] = tb + loc[i];
    }
    if (t == 0) rowptr[NN] = NE;
}

// ---------------------------------------------------------------------------
// p-compute: p[n][m] = h[n,:] @ (U[m,:] * sc)  — one (node,head) per thread.
// FOLD: sc[k] from BN stats; shift term cancels in logit differences.
// ---------------------------------------------------------------------------
template <int FOLD>
__device__ __forceinline__ void dev_pk(const float* __restrict__ h,
                                       const float* __restrict__ U,
                                       const float* __restrict__ stats,
                                       const float* __restrict__ g,
                                       float* __restrict__ pout, int vb) {
    __shared__ float usc_s[4][64];
    int t = threadIdx.x;
    {
        int m = t >> 6, k = t & 63;
        float sc = 1.0f;
        if (FOLD) {
            const float invN = 1.0f / (float)NN;
            float mu = stats[k] * invN;
            float var = stats[64 + k] * invN - mu * mu;
            sc = rsqrtf(var + BN_EPS) * g[k];
        }
        usc_s[m][k] = U[m * 64 + k] * sc;
    }
    __syncthreads();
    int idx = vb * 256 + t;
    if (idx < NN * 4) {
        int n = idx >> 2, m = idx & 3;
        const float4* hn = reinterpret_cast<const float4*>(h) + (size_t)n * 16;
        const float* um = usc_s[m];
        float a = 0.0f;
#pragma unroll
        for (int j = 0; j < 16; ++j) {
            float4 hv = hn[j];
            a += hv.x * um[4 * j + 0] + hv.y * um[4 * j + 1] +
                 hv.z * um[4 * j + 2] + hv.w * um[4 * j + 3];
        }
        pout[idx] = a;
    }
}

template <int FOLD>
__global__ __launch_bounds__(256) void k_pk(const float* __restrict__ h,
                                            const float* __restrict__ U,
                                            const float* __restrict__ stats,
                                            const float* __restrict__ g,
                                            float* __restrict__ pout) {
    dev_pk<FOLD>(h, U, stats, g, pout, blockIdx.x);
}

// ---------------------------------------------------------------------------
// Fused: blocks 0..1874 scatter CSR; blocks 1875.. compute p0 = x@U0^T.
// Block-uniform divergence; dev_pk<0> has a sync, scatter branch has none.
// ---------------------------------------------------------------------------
__global__ __launch_bounds__(256) void k_scatter_pk0(const void* __restrict__ ei,
                                                     const int* __restrict__ rowptr,
                                                     int* __restrict__ cursor,
                                                     int* __restrict__ csr,
                                                     const float* __restrict__ x,
                                                     const float* __restrict__ U0,
                                                     float* __restrict__ p) {
    if (blockIdx.x < EBLK) {
        int is64 = detect64((const unsigned int*)ei);
        int e = blockIdx.x * 256 + threadIdx.x;
        int s = load_idx(ei, is64, e);
        int d = load_idx(ei, is64, NE + e);
        int pos = rowptr[d] + atomicAdd(&cursor[d], 1);
        csr[pos] = s;
    } else {
        dev_pk<0>(x, U0, nullptr, nullptr, p, blockIdx.x - EBLK);
    }
}

// ---------------------------------------------------------------------------
// Aggregate (pre-GEMM form): wave per dst node, lane = feature channel k.
// Gathers 128 B/edge of bf16 features (hbf, 3.84 MB -> L2-resident) instead
// of 512 B/edge of transformed y2 (15.4 MB, L3). Produces
//   z[n][m][k]  = (1/D) * [ selfattn_m*h_n[k] + sum_e attn_em * h_src[k] ]
//   zs[n][m]    = (1/D) * [ selfattn_m        + sum_e attn_em            ]
// The per-layer GEMM with W (and BN fold) happens in k_post.
// ---------------------------------------------------------------------------
__global__ __launch_bounds__(256) void k_agg(const int* __restrict__ rowptr,
                                             const int* __restrict__ csr,
                                             const float* __restrict__ p,
                                             const ushort* __restrict__ hbf,
                                             const float* __restrict__ cvec,
                                             ushort* __restrict__ z,
                                             float* __restrict__ zs) {
    __shared__ float4 attn_s[4][64];
    __shared__ int src_s[4][64];
    int wid = threadIdx.x >> 6;
    int lane = threadIdx.x & 63;
    int n = blockIdx.x * 4 + wid;
    const float4* p4 = reinterpret_cast<const float4*>(p);

    float4 cv = make_float4(cvec[0], cvec[1], cvec[2], cvec[3]);
    // self-loop attention = softmax(c), node-independent
    float smx = fmaxf(fmaxf(cv.x, cv.y), fmaxf(cv.z, cv.w));
    float se0 = __expf(cv.x - smx), se1 = __expf(cv.y - smx);
    float se2 = __expf(cv.z - smx), se3 = __expf(cv.w - smx);
    float sinv = 1.0f / (se0 + se1 + se2 + se3);
    float sl0 = se0 * sinv, sl1 = se1 * sinv, sl2 = se2 * sinv, sl3 = se3 * sinv;

    float4 pd = p4[n];
    float4 pdc = make_float4(pd.x + cv.x, pd.y + cv.y, pd.z + cv.z, pd.w + cv.w);
    float hs = bf2f(hbf[(unsigned)(n * 64 + lane)]);
    float acc0 = sl0 * hs, acc1 = sl1 * hs, acc2 = sl2 * hs, acc3 = sl3 * hs;
    float zt0 = sl0, zt1 = sl1, zt2 = sl2, zt3 = sl3;

    int start = rowptr[n];
    int end = rowptr[n + 1];
    for (int j = start; j < end; j += 64) {
        int chunk = end - j;
        if (chunk > 64) chunk = 64;
        if (lane < chunk) {
            int s = csr[j + lane];
            float4 q = p4[(unsigned)s];
            float l0 = pdc.x - q.x;
            float l1 = pdc.y - q.y;
            float l2 = pdc.z - q.z;
            float l3 = pdc.w - q.w;
            float mx = fmaxf(fmaxf(l0, l1), fmaxf(l2, l3));  // REQUIRED (R5 NaN)
            float e0 = __expf(l0 - mx);
            float e1 = __expf(l1 - mx);
            float e2 = __expf(l2 - mx);
            float e3 = __expf(l3 - mx);
            float inv = 1.0f / (e0 + e1 + e2 + e3);
            attn_s[wid][lane] = make_float4(e0 * inv, e1 * inv, e2 * inv, e3 * inv);
            src_s[wid][lane] = s;
        }
        int k = 0;
        for (; k + 4 <= chunk; k += 4) {
            float4 a0 = attn_s[wid][k];
            int s0 = src_s[wid][k];
            float4 a1 = attn_s[wid][k + 1];
            int s1 = src_s[wid][k + 1];
            float4 a2 = attn_s[wid][k + 2];
            int s2 = src_s[wid][k + 2];
            float4 a3 = attn_s[wid][k + 3];
            int s3 = src_s[wid][k + 3];
            float h0 = bf2f(hbf[(unsigned)(s0 * 64 + lane)]);
            float h1 = bf2f(hbf[(unsigned)(s1 * 64 + lane)]);
            float h2 = bf2f(hbf[(unsigned)(s2 * 64 + lane)]);
            float h3 = bf2f(hbf[(unsigned)(s3 * 64 + lane)]);
            acc0 += a0.x * h0 + a1.x * h1 + a2.x * h2 + a3.x * h3;
            acc1 += a0.y * h0 + a1.y * h1 + a2.y * h2 + a3.y * h3;
            acc2 += a0.z * h0 + a1.z * h1 + a2.z * h2 + a3.z * h3;
            acc3 += a0.w * h0 + a1.w * h1 + a2.w * h2 + a3.w * h3;
            zt0 += a0.x + a1.x + a2.x + a3.x;
            zt1 += a0.y + a1.y + a2.y + a3.y;
            zt2 += a0.z + a1.z + a2.z + a3.z;
            zt3 += a0.w + a1.w + a2.w + a3.w;
        }
        for (; k < chunk; ++k) {
            float4 a0 = attn_s[wid][k];
            int s0 = src_s[wid][k];
            float h0 = bf2f(hbf[(unsigned)(s0 * 64 + lane)]);
            acc0 += a0.x * h0;
            acc1 += a0.y * h0;
            acc2 += a0.z * h0;
            acc3 += a0.w * h0;
            zt0 += a0.x; zt1 += a0.y; zt2 += a0.z; zt3 += a0.w;
        }
    }

    float invD = 1.0f / (float)(end - start + 1);
    unsigned base = (unsigned)n * 256 + lane;
    __builtin_nontemporal_store(f2bf(acc0 * invD), &z[base]);
    __builtin_nontemporal_store(f2bf(acc1 * invD), &z[base + 64]);
    __builtin_nontemporal_store(f2bf(acc2 * invD), &z[base + 128]);
    __builtin_nontemporal_store(f2bf(acc3 * invD), &z[base + 192]);
    if (lane == 0) {
        reinterpret_cast<float4*>(zs)[n] =
            make_float4(zt0 * invD, zt1 * invD, zt2 * invD, zt3 * invD);
    }
}

// ---------------------------------------------------------------------------
// Post: node-local GEMM  out[n][o] = sum_m z[n][m] @ (W_m * sc)^T
//                                   + sum_m zs[n][m]*cstv[m][o] + b[o]
// with cstv[m][o] = sum_k sh[k]*W[(m*64+o)*64+k]  (BN shift through W).
// 16 nodes/block; per-m W tile in LDS [64][65] (conflict-free), z in LDS.
// STATS: relu + h fp32 + hbf bf16 + per-channel sum/sumsq atomics.
// ---------------------------------------------------------------------------
template <int FOLD, int STATS>
__global__ __launch_bounds__(256) void k_post(const ushort* __restrict__ z,
                                              const float* __restrict__ zsg,
                                              const float* __restrict__ W,
                                              const float* __restrict__ stats_in,
                                              const float* __restrict__ g,
                                              const float* __restrict__ bt,
                                              const float* __restrict__ bvec,
                                              float* __restrict__ hout,
                                              ushort* __restrict__ hbfout,
                                              float* __restrict__ stats_out) {
    __shared__ float sc_s[64];
    __shared__ float sh_s[64];
    __shared__ float cstv_s[256];
    __shared__ float z_s[16][256];
    __shared__ float w_s[64][65];
    __shared__ float zs_s[16][4];
    __shared__ float s1m[256];
    __shared__ float s2m[256];

    int t = threadIdx.x;
    int n0 = blockIdx.x * 16;

    if (FOLD) {
        if (t < 64) {
            const float invN = 1.0f / (float)NN;
            float mu = stats_in[t] * invN;
            float var = stats_in[64 + t] * invN - mu * mu;
            float sc = rsqrtf(var + BN_EPS) * g[t];
            sc_s[t] = sc;
            sh_s[t] = bt[t] - mu * sc;
        }
        __syncthreads();
        {
            float s = 0.0f;
            const float* wr = W + (size_t)t * 64;
#pragma unroll 8
            for (int k = 0; k < 64; ++k) s += sh_s[k] * wr[k];
            cstv_s[t] = s;
        }
    }

    // load z tile (16 nodes x 256 ch bf16 = 8 KB) -> fp32 LDS
    {
        const uint4* zr = reinterpret_cast<const uint4*>(z + (size_t)n0 * 256);
        float* zd = &z_s[0][0];
#pragma unroll
        for (int i = t; i < 512; i += 256) {
            uint4 v = zr[i];
            float* d = zd + i * 8;
            d[0] = bf2f((unsigned short)(v.x));
            d[1] = bf2f((unsigned short)(v.x >> 16));
            d[2] = bf2f((unsigned short)(v.y));
            d[3] = bf2f((unsigned short)(v.y >> 16));
            d[4] = bf2f((unsigned short)(v.z));
            d[5] = bf2f((unsigned short)(v.z >> 16));
            d[6] = bf2f((unsigned short)(v.w));
            d[7] = bf2f((unsigned short)(v.w >> 16));
        }
    }
    if (FOLD && t < 64) (&zs_s[0][0])[t] = zsg[n0 * 4 + t];
    __syncthreads();

    int o = t & 63;
    int quad = t >> 6;
    float acc[4] = {0.0f, 0.0f, 0.0f, 0.0f};

    for (int m = 0; m < 4; ++m) {
        // load W tile for this m, scaled by sc (coalesced: lane = k)
        {
            int k = t & 63;
            int ob = t >> 6;
            float scale = FOLD ? sc_s[k] : 1.0f;
            const float* Wm = W + ((size_t)m * 64) * 64;
#pragma unroll
            for (int jj = 0; jj < 16; ++jj) {
                int oo = ob + 4 * jj;
                w_s[oo][k] = Wm[(size_t)oo * 64 + k] * scale;
            }
        }
        __syncthreads();
        const float* z0 = &z_s[quad * 4 + 0][m * 64];
        const float* z1 = &z_s[quad * 4 + 1][m * 64];
        const float* z2 = &z_s[quad * 4 + 2][m * 64];
        const float* z3 = &z_s[quad * 4 + 3][m * 64];
        const float* wr = w_s[o];
#pragma unroll
        for (int k = 0; k < 64; ++k) {
            float w = wr[k];
            acc[0] += z0[k] * w;
            acc[1] += z1[k] * w;
            acc[2] += z2[k] * w;
            acc[3] += z3[k] * w;
        }
        __syncthreads();
    }

    float bval = bvec[o];
    float ls = 0.0f, lq = 0.0f;
#pragma unroll
    for (int j = 0; j < 4; ++j) {
        int ni = quad * 4 + j;
        int n = n0 + ni;
        float v = acc[j] + bval;
        if (FOLD) {
            v += zs_s[ni][0] * cstv_s[o] + zs_s[ni][1] * cstv_s[64 + o] +
                 zs_s[ni][2] * cstv_s[128 + o] + zs_s[ni][3] * cstv_s[192 + o];
        }
        if (STATS) {
            v = fmaxf(v, 0.0f);
            hout[(size_t)n * 64 + o] = v;
            hbfout[(size_t)n * 64 + o] = f2bf(v);
            ls += v;
            lq += v * v;
        } else {
            hout[(size_t)n * 64 + o] = v;
        }
    }

    if (STATS) {
        s1m[t] = ls;
        s2m[t] = lq;
        __syncthreads();
        if (t < 64) {
            float s = s1m[t] + s1m[t + 64] + s1m[t + 128] + s1m[t + 192];
            float q = s2m[t] + s2m[t + 64] + s2m[t + 128] + s2m[t + 192];
            atomicAdd(&stats_out[t], s);
            atomicAdd(&stats_out[64 + t], q);
        }
    }
}

extern "C" void kernel_launch(void* const* d_in, const int* in_sizes, int n_in,
                              void* d_out, int out_size, void* d_ws, size_t ws_size,
                              hipStream_t stream) {
    const float* x = (const float*)d_in[0];
    const void* ei = d_in[1];
    const float* W0 = (const float*)d_in[2];
    const float* U0 = (const float*)d_in[3];
    const float* c0 = (const float*)d_in[4];
    const float* b0 = (const float*)d_in[5];
    const float* g0 = (const float*)d_in[6];
    const float* bt0 = (const float*)d_in[7];
    const float* W1 = (const float*)d_in[8];
    const float* U1 = (const float*)d_in[9];
    const float* c1 = (const float*)d_in[10];
    const float* b1 = (const float*)d_in[11];
    const float* g1 = (const float*)d_in[12];
    const float* bt1 = (const float*)d_in[13];
    const float* W2 = (const float*)d_in[14];
    const float* U2 = (const float*)d_in[15];
    const float* c2 = (const float*)d_in[16];
    const float* b2 = (const float*)d_in[17];

    // workspace layout (all 16B-aligned)
    ushort* xbf = (ushort*)d_ws;                      // NN*64
    ushort* hbf = xbf + (size_t)NN * 64;              // NN*64
    ushort* z = hbf + (size_t)NN * 64;                // NN*256 (15.36 MB)
    float* zs = (float*)(z + (size_t)NN * 256);       // NN*4
    float* h = zs + (size_t)NN * 4;                   // NN*64
    float* p = h + (size_t)NN * 64;                   // NN*4
    int* degi = (int*)(p + (size_t)NN * 4);           // NN   } zeroed as one
    int* cursor = degi + NN;                          // NN   } int4 region
    float* stats01 = (float*)(cursor + NN);           // 256  } (15064 int4)
    int* rowptr = (int*)(stats01 + 256);              // NN+1
    int* csr = rowptr + NN + 1;                       // NE
    float* stats0 = stats01;
    float* stats1 = stats01 + 128;

    const int prepBlocks = (480000 + 15064 + 255) / 256;  // 1934

    // 12 dispatches
    k_prep<<<prepBlocks, 256, 0, stream>>>(x, xbf, (int4*)degi);
    k_hist<<<EBLK, 256, 0, stream>>>(ei, degi);
    k_scan<<<1, 1024, 0, stream>>>(degi, rowptr);
    k_scatter_pk0<<<EBLK + PKBLK, 256, 0, stream>>>(ei, rowptr, cursor, csr,
                                                    x, U0, p);

    // ---- layer 0 (no BN in front) ----
    k_agg<<<AGGBLK, 256, 0, stream>>>(rowptr, csr, p, xbf, c0, z, zs);
    k_post<0, 1><<<POSTBLK, 256, 0, stream>>>(z, zs, W0, nullptr, nullptr,
                                              nullptr, b0, h, hbf, stats0);
    // ---- layer 1 (BN0 folded via stats0) ----
    k_pk<1><<<PKBLK, 256, 0, stream>>>(h, U1, stats0, g0, p);
    k_agg<<<AGGBLK, 256, 0, stream>>>(rowptr, csr, p, hbf, c1, z, zs);
    k_post<1, 1><<<POSTBLK, 256, 0, stream>>>(z, zs, W1, stats0, g0, bt0, b1,
                                              h, hbf, stats1);
    // ---- layer 2 (BN1 folded via stats1) ----
    k_pk<1><<<PKBLK, 256, 0, stream>>>(h, U2, stats1, g1, p);
    k_agg<<<AGGBLK, 256, 0, stream>>>(rowptr, csr, p, hbf, c2, z, zs);
    k_post<1, 0><<<POSTBLK, 256, 0, stream>>>(z, zs, W2, stats1, g1, bt1, b2,
                                              (float*)d_out, nullptr, nullptr);
}

// Round 4
// 430.720 us; speedup vs baseline: 4.7655x; 1.0727x over previous
//
#include <hip/hip_runtime.h>

#define NN 30000
#define NE 480000
#define BN_EPS 1e-5f
#define EBLK 1875     // NE/256 edge blocks
#define AGGBLK 7500   // wave per node
#define POSTBLK 938   // 32 nodes per block (8 per wave), last block guarded
#define PKBLK 469     // ceil(NN*4/256)

// ---------------------------------------------------------------------------
// bf16 helpers (RNE pack, cheap unpack)
// ---------------------------------------------------------------------------
__device__ __forceinline__ unsigned short f2bf(float x) {
    unsigned int u = __float_as_uint(x);
    return (unsigned short)((u + 0x7fffu + ((u >> 16) & 1u)) >> 16);
}
__device__ __forceinline__ float bf2f(unsigned short h) {
    return __uint_as_float(((unsigned int)h) << 16);
}

// int64-vs-int32 detect: odd 32-bit words of int64 indices < 2^31 are all 0.
__device__ __forceinline__ int detect64(const unsigned int* __restrict__ ei) {
    unsigned int v = ei[1] | ei[3] | ei[5] | ei[7] |
                     ei[9] | ei[11] | ei[13] | ei[15];
    return v == 0u;
}
__device__ __forceinline__ int load_idx(const void* ei, int is64, int pos) {
    if (is64) return (int)((const long long*)ei)[pos];
    return ((const int*)ei)[pos];
}

// ---------------------------------------------------------------------------
// prep: x -> xbf (bf16), zero degi+cursor+stats, build wt2:
//   wt2[layer][j4*256 + o*4 + q] = W_layer[(m*64+o)*64 + k],  j=j4*4+q,
//   m=j>>6, k=j&63.  Post reads float4 wt2f4[j4*64+o] = W for 4 consecutive j.
// ---------------------------------------------------------------------------
__global__ __launch_bounds__(256) void k_prep(const float* __restrict__ x,
                                              const float* __restrict__ W0,
                                              const float* __restrict__ W1,
                                              const float* __restrict__ W2,
                                              ushort* __restrict__ xbf,
                                              int4* __restrict__ zerobase,
                                              float* __restrict__ wt2) {
    int t = blockIdx.x * 256 + threadIdx.x;
    if (t < 480000) {  // NN*64/4 float4s
        float4 v = reinterpret_cast<const float4*>(x)[t];
        ushort4 o;
        o.x = f2bf(v.x); o.y = f2bf(v.y); o.z = f2bf(v.z); o.w = f2bf(v.w);
        reinterpret_cast<ushort4*>(xbf)[t] = o;
    } else if (t < 480000 + 15064) {  // (2*NN ints + 256 floats)/4
        zerobase[t - 480000] = make_int4(0, 0, 0, 0);
    } else if (t < 480000 + 15064 + 49152) {
        int t2 = t - (480000 + 15064);
        int layer = t2 >> 14;
        int r = t2 & 16383;
        int j4 = r >> 8;
        int o = (r >> 2) & 63;
        int q = r & 3;
        int j = j4 * 4 + q;
        int m = j >> 6;
        int k = j & 63;
        const float* W = (layer == 0) ? W0 : (layer == 1) ? W1 : W2;
        wt2[t2] = W[(m * 64 + o) * 64 + k];
    }
}

// ---------------------------------------------------------------------------
// hist: dst-degree histogram (exactly NE threads)
// ---------------------------------------------------------------------------
__global__ __launch_bounds__(256) void k_hist(const void* __restrict__ ei,
                                              int* __restrict__ degi) {
    int e = blockIdx.x * 256 + threadIdx.x;
    int is64 = detect64((const unsigned int*)ei);
    int d = load_idx(ei, is64, NE + e);
    atomicAdd(&degi[d], 1);
}

// ---------------------------------------------------------------------------
// scan: ONE block, 1024 threads, 30 elems/thread -> exclusive rowptr.
// ---------------------------------------------------------------------------
__global__ __launch_bounds__(1024) void k_scan(const int* __restrict__ degi,
                                               int* __restrict__ rowptr) {
    __shared__ int sm[1024];
    const int PER = 30;
    int t = threadIdx.x;
    int base = t * PER;
    int loc[PER];
    int sum = 0;
#pragma unroll
    for (int i = 0; i < PER; ++i) {
        int idx = base + i;
        int d = (idx < NN) ? degi[idx] : 0;
        loc[i] = sum;
        sum += d;
    }
    sm[t] = sum;
    __syncthreads();
    for (int off = 1; off < 1024; off <<= 1) {
        int add = (t >= off) ? sm[t - off] : 0;
        __syncthreads();
        sm[t] += add;
        __syncthreads();
    }
    int tb = sm[t] - sum;
#pragma unroll
    for (int i = 0; i < PER; ++i) {
        int idx = base + i;
        if (idx < NN) rowptr[idx] = tb + loc[i];
    }
    if (t == 0) rowptr[NN] = NE;
}

// ---------------------------------------------------------------------------
// p-compute: p[n][m] = h[n,:] @ (U[m,:] * sc)  — one (node,head) per thread.
// ---------------------------------------------------------------------------
template <int FOLD>
__device__ __forceinline__ void dev_pk(const float* __restrict__ h,
                                       const float* __restrict__ U,
                                       const float* __restrict__ stats,
                                       const float* __restrict__ g,
                                       float* __restrict__ pout, int vb) {
    __shared__ float usc_s[4][64];
    int t = threadIdx.x;
    {
        int m = t >> 6, k = t & 63;
        float sc = 1.0f;
        if (FOLD) {
            const float invN = 1.0f / (float)NN;
            float mu = stats[k] * invN;
            float var = stats[64 + k] * invN - mu * mu;
            sc = rsqrtf(var + BN_EPS) * g[k];
        }
        usc_s[m][k] = U[m * 64 + k] * sc;
    }
    __syncthreads();
    int idx = vb * 256 + t;
    if (idx < NN * 4) {
        int n = idx >> 2, m = idx & 3;
        const float4* hn = reinterpret_cast<const float4*>(h) + (size_t)n * 16;
        const float* um = usc_s[m];
        float a = 0.0f;
#pragma unroll
        for (int j = 0; j < 16; ++j) {
            float4 hv = hn[j];
            a += hv.x * um[4 * j + 0] + hv.y * um[4 * j + 1] +
                 hv.z * um[4 * j + 2] + hv.w * um[4 * j + 3];
        }
        pout[idx] = a;
    }
}

template <int FOLD>
__global__ __launch_bounds__(256) void k_pk(const float* __restrict__ h,
                                            const float* __restrict__ U,
                                            const float* __restrict__ stats,
                                            const float* __restrict__ g,
                                            float* __restrict__ pout) {
    dev_pk<FOLD>(h, U, stats, g, pout, blockIdx.x);
}

// ---------------------------------------------------------------------------
// Fused: blocks 0..1874 scatter CSR; blocks 1875.. compute p0 = x@U0^T.
// ---------------------------------------------------------------------------
__global__ __launch_bounds__(256) void k_scatter_pk0(const void* __restrict__ ei,
                                                     const int* __restrict__ rowptr,
                                                     int* __restrict__ cursor,
                                                     int* __restrict__ csr,
                                                     const float* __restrict__ x,
                                                     const float* __restrict__ U0,
                                                     float* __restrict__ p) {
    if (blockIdx.x < EBLK) {
        int is64 = detect64((const unsigned int*)ei);
        int e = blockIdx.x * 256 + threadIdx.x;
        int s = load_idx(ei, is64, e);
        int d = load_idx(ei, is64, NE + e);
        int pos = rowptr[d] + atomicAdd(&cursor[d], 1);
        csr[pos] = s;
    } else {
        dev_pk<0>(x, U0, nullptr, nullptr, p, blockIdx.x - EBLK);
    }
}

// ---------------------------------------------------------------------------
// Aggregate: wave per dst node, lane = feature channel k. Gathers 128 B/edge
// of bf16 features (hbf, 3.84 MB, L2-resident). FOLD: scales the feature
// accumulators by BN sc[lane] (stats of the PREVIOUS layer are complete by
// the time this launches) so k_post is a pure GEMM. zs stays unscaled (it
// multiplies cstv which carries the BN shift).
//   z[n][m][k] = invD * sc[k] * [ selfattn_m*h_n[k] + sum_e attn_em*h_src[k] ]
//   zs[n][m]   = invD *        [ selfattn_m         + sum_e attn_em          ]
// ---------------------------------------------------------------------------
template <int FOLD>
__global__ __launch_bounds__(256) void k_agg(const int* __restrict__ rowptr,
                                             const int* __restrict__ csr,
                                             const float* __restrict__ p,
                                             const ushort* __restrict__ hbf,
                                             const float* __restrict__ cvec,
                                             const float* __restrict__ stats_in,
                                             const float* __restrict__ g,
                                             ushort* __restrict__ z,
                                             float* __restrict__ zs) {
    __shared__ float4 attn_s[4][64];
    __shared__ int src_s[4][64];
    int wid = threadIdx.x >> 6;
    int lane = threadIdx.x & 63;
    int n = blockIdx.x * 4 + wid;
    const float4* p4 = reinterpret_cast<const float4*>(p);

    float scl = 1.0f;
    if (FOLD) {
        const float invN = 1.0f / (float)NN;
        float mu = stats_in[lane] * invN;
        float var = stats_in[64 + lane] * invN - mu * mu;
        scl = rsqrtf(var + BN_EPS) * g[lane];
    }

    float4 cv = make_float4(cvec[0], cvec[1], cvec[2], cvec[3]);
    float smx = fmaxf(fmaxf(cv.x, cv.y), fmaxf(cv.z, cv.w));
    float se0 = __expf(cv.x - smx), se1 = __expf(cv.y - smx);
    float se2 = __expf(cv.z - smx), se3 = __expf(cv.w - smx);
    float sinv = 1.0f / (se0 + se1 + se2 + se3);
    float sl0 = se0 * sinv, sl1 = se1 * sinv, sl2 = se2 * sinv, sl3 = se3 * sinv;

    float4 pd = p4[n];
    float4 pdc = make_float4(pd.x + cv.x, pd.y + cv.y, pd.z + cv.z, pd.w + cv.w);
    float hs = bf2f(hbf[(unsigned)(n * 64 + lane)]);
    float acc0 = sl0 * hs, acc1 = sl1 * hs, acc2 = sl2 * hs, acc3 = sl3 * hs;
    float zt0 = sl0, zt1 = sl1, zt2 = sl2, zt3 = sl3;

    int start = rowptr[n];
    int end = rowptr[n + 1];
    for (int j = start; j < end; j += 64) {
        int chunk = end - j;
        if (chunk > 64) chunk = 64;
        if (lane < chunk) {
            int s = csr[j + lane];
            float4 q = p4[(unsigned)s];
            float l0 = pdc.x - q.x;
            float l1 = pdc.y - q.y;
            float l2 = pdc.z - q.z;
            float l3 = pdc.w - q.w;
            float mx = fmaxf(fmaxf(l0, l1), fmaxf(l2, l3));  // REQUIRED (R5 NaN)
            float e0 = __expf(l0 - mx);
            float e1 = __expf(l1 - mx);
            float e2 = __expf(l2 - mx);
            float e3 = __expf(l3 - mx);
            float inv = 1.0f / (e0 + e1 + e2 + e3);
            attn_s[wid][lane] = make_float4(e0 * inv, e1 * inv, e2 * inv, e3 * inv);
            src_s[wid][lane] = s;
        }
        int k = 0;
        for (; k + 4 <= chunk; k += 4) {
            float4 a0 = attn_s[wid][k];
            int s0 = src_s[wid][k];
            float4 a1 = attn_s[wid][k + 1];
            int s1 = src_s[wid][k + 1];
            float4 a2 = attn_s[wid][k + 2];
            int s2 = src_s[wid][k + 2];
            float4 a3 = attn_s[wid][k + 3];
            int s3 = src_s[wid][k + 3];
            float h0 = bf2f(hbf[(unsigned)(s0 * 64 + lane)]);
            float h1 = bf2f(hbf[(unsigned)(s1 * 64 + lane)]);
            float h2 = bf2f(hbf[(unsigned)(s2 * 64 + lane)]);
            float h3 = bf2f(hbf[(unsigned)(s3 * 64 + lane)]);
            acc0 += a0.x * h0 + a1.x * h1 + a2.x * h2 + a3.x * h3;
            acc1 += a0.y * h0 + a1.y * h1 + a2.y * h2 + a3.y * h3;
            acc2 += a0.z * h0 + a1.z * h1 + a2.z * h2 + a3.z * h3;
            acc3 += a0.w * h0 + a1.w * h1 + a2.w * h2 + a3.w * h3;
            zt0 += a0.x + a1.x + a2.x + a3.x;
            zt1 += a0.y + a1.y + a2.y + a3.y;
            zt2 += a0.z + a1.z + a2.z + a3.z;
            zt3 += a0.w + a1.w + a2.w + a3.w;
        }
        for (; k < chunk; ++k) {
            float4 a0 = attn_s[wid][k];
            int s0 = src_s[wid][k];
            float h0 = bf2f(hbf[(unsigned)(s0 * 64 + lane)]);
            acc0 += a0.x * h0;
            acc1 += a0.y * h0;
            acc2 += a0.z * h0;
            acc3 += a0.w * h0;
            zt0 += a0.x; zt1 += a0.y; zt2 += a0.z; zt3 += a0.w;
        }
    }

    float invD = 1.0f / (float)(end - start + 1);
    float s = invD * scl;
    unsigned base = (unsigned)n * 256 + lane;
    __builtin_nontemporal_store(f2bf(acc0 * s), &z[base]);
    __builtin_nontemporal_store(f2bf(acc1 * s), &z[base + 64]);
    __builtin_nontemporal_store(f2bf(acc2 * s), &z[base + 128]);
    __builtin_nontemporal_store(f2bf(acc3 * s), &z[base + 192]);
    if (lane == 0) {
        reinterpret_cast<float4*>(zs)[n] =
            make_float4(zt0 * invD, zt1 * invD, zt2 * invD, zt3 * invD);
    }
}

// ---------------------------------------------------------------------------
// Post (register GEMM, R2-transform style — NO LDS in the hot loop):
//   out[n][o] = sum_j z[n][j] * wt2[j][o]  + sum_m zs[n][m]*cstv[m*64+o] + b[o]
// Wave = 8 nodes, lane = o. Per j4 step: one coalesced float4 w load
// (reused 8x) + 8 broadcast uint2 z loads + 32 FMA. 938 blocks.
// ---------------------------------------------------------------------------
template <int FOLD, int STATS>
__global__ __launch_bounds__(256) void k_post(const float4* __restrict__ wl,
                                              const ushort* __restrict__ z,
                                              const float* __restrict__ zsg,
                                              const float* __restrict__ W,
                                              const float* __restrict__ stats_in,
                                              const float* __restrict__ g,
                                              const float* __restrict__ bt,
                                              const float* __restrict__ bvec,
                                              float* __restrict__ hout,
                                              ushort* __restrict__ hbfout,
                                              float* __restrict__ stats_out) {
    __shared__ float cstv_s[256];
    __shared__ float red_s[256];
    int t = threadIdx.x;

    if (FOLD) {
        __shared__ float sh_s[64];
        if (t < 64) {
            const float invN = 1.0f / (float)NN;
            float mu = stats_in[t] * invN;
            float var = stats_in[64 + t] * invN - mu * mu;
            float sc = rsqrtf(var + BN_EPS) * g[t];
            sh_s[t] = bt[t] - mu * sc;
        }
        __syncthreads();
        float s = 0.0f;
        const float* wr = W + (size_t)t * 64;
#pragma unroll 8
        for (int k = 0; k < 64; ++k) s += sh_s[k] * wr[k];
        cstv_s[t] = s;
        __syncthreads();
    }

    int lane = t & 63;
    int wid = t >> 6;
    int n0 = blockIdx.x * 32 + wid * 8;

    float acc[8];
#pragma unroll
    for (int jn = 0; jn < 8; ++jn) acc[jn] = 0.0f;

    const uint2* zp[8];
#pragma unroll
    for (int jn = 0; jn < 8; ++jn) {
        int nl = n0 + jn;
        if (nl > NN - 1) nl = NN - 1;  // clamp loads; stores guarded below
        zp[jn] = reinterpret_cast<const uint2*>(z) + (size_t)nl * 64;
    }

#pragma unroll 2
    for (int j4 = 0; j4 < 64; ++j4) {
        float4 w = wl[j4 * 64 + lane];
#pragma unroll
        for (int jn = 0; jn < 8; ++jn) {
            uint2 zv = zp[jn][j4];
            float z0 = bf2f((unsigned short)zv.x);
            float z1 = bf2f((unsigned short)(zv.x >> 16));
            float z2 = bf2f((unsigned short)zv.y);
            float z3 = bf2f((unsigned short)(zv.y >> 16));
            acc[jn] += z0 * w.x + z1 * w.y + z2 * w.z + z3 * w.w;
        }
    }

    float bval = bvec[lane];
    float ls = 0.0f, lq = 0.0f;
#pragma unroll
    for (int jn = 0; jn < 8; ++jn) {
        int n = n0 + jn;
        if (n < NN) {
            float v = acc[jn] + bval;
            if (FOLD) {
                float4 zs4 = reinterpret_cast<const float4*>(zsg)[n];
                v += zs4.x * cstv_s[lane] + zs4.y * cstv_s[64 + lane] +
                     zs4.z * cstv_s[128 + lane] + zs4.w * cstv_s[192 + lane];
            }
            if (STATS) {
                v = fmaxf(v, 0.0f);
                hout[(size_t)n * 64 + lane] = v;
                hbfout[(size_t)n * 64 + lane] = f2bf(v);
                ls += v;
                lq += v * v;
            } else {
                hout[(size_t)n * 64 + lane] = v;
            }
        }
    }

    if (STATS) {
        red_s[t] = ls;
        __syncthreads();
        if (t < 64)
            atomicAdd(&stats_out[t],
                      red_s[t] + red_s[t + 64] + red_s[t + 128] + red_s[t + 192]);
        __syncthreads();
        red_s[t] = lq;
        __syncthreads();
        if (t < 64)
            atomicAdd(&stats_out[64 + t],
                      red_s[t] + red_s[t + 64] + red_s[t + 128] + red_s[t + 192]);
    }
}

extern "C" void kernel_launch(void* const* d_in, const int* in_sizes, int n_in,
                              void* d_out, int out_size, void* d_ws, size_t ws_size,
                              hipStream_t stream) {
    const float* x = (const float*)d_in[0];
    const void* ei = d_in[1];
    const float* W0 = (const float*)d_in[2];
    const float* U0 = (const float*)d_in[3];
    const float* c0 = (const float*)d_in[4];
    const float* b0 = (const float*)d_in[5];
    const float* g0 = (const float*)d_in[6];
    const float* bt0 = (const float*)d_in[7];
    const float* W1 = (const float*)d_in[8];
    const float* U1 = (const float*)d_in[9];
    const float* c1 = (const float*)d_in[10];
    const float* b1 = (const float*)d_in[11];
    const float* g1 = (const float*)d_in[12];
    const float* bt1 = (const float*)d_in[13];
    const float* W2 = (const float*)d_in[14];
    const float* U2 = (const float*)d_in[15];
    const float* c2 = (const float*)d_in[16];
    const float* b2 = (const float*)d_in[17];

    // workspace layout (all 16B-aligned)
    ushort* xbf = (ushort*)d_ws;                      // NN*64
    ushort* hbf = xbf + (size_t)NN * 64;              // NN*64
    ushort* z = hbf + (size_t)NN * 64;                // NN*256 (15.36 MB)
    float* zs = (float*)(z + (size_t)NN * 256);       // NN*4
    float* h = zs + (size_t)NN * 4;                   // NN*64
    float* p = h + (size_t)NN * 64;                   // NN*4
    int* degi = (int*)(p + (size_t)NN * 4);           // NN   } zeroed as one
    int* cursor = degi + NN;                          // NN   } int4 region
    float* stats01 = (float*)(cursor + NN);           // 256  } (15064 int4)
    int* rowptr = (int*)(stats01 + 256);              // NN+1
    int* csr = rowptr + NN + 1;                       // NE
    float* wt2 = (float*)(csr + NE);                  // 3*16384
    float* stats0 = stats01;
    float* stats1 = stats01 + 128;

    const int prepBlocks = (480000 + 15064 + 49152 + 255) / 256;  // 2126

    // 12 dispatches
    k_prep<<<prepBlocks, 256, 0, stream>>>(x, W0, W1, W2, xbf, (int4*)degi, wt2);
    k_hist<<<EBLK, 256, 0, stream>>>(ei, degi);
    k_scan<<<1, 1024, 0, stream>>>(degi, rowptr);
    k_scatter_pk0<<<EBLK + PKBLK, 256, 0, stream>>>(ei, rowptr, cursor, csr,
                                                    x, U0, p);

    const float4* wl0 = (const float4*)wt2;
    const float4* wl1 = (const float4*)(wt2 + 16384);
    const float4* wl2 = (const float4*)(wt2 + 32768);

    // ---- layer 0 (no BN in front) ----
    k_agg<0><<<AGGBLK, 256, 0, stream>>>(rowptr, csr, p, xbf, c0, nullptr,
                                         nullptr, z, zs);
    k_post<0, 1><<<POSTBLK, 256, 0, stream>>>(wl0, z, zs, W0, nullptr, nullptr,
                                              nullptr, b0, h, hbf, stats0);
    // ---- layer 1 (BN0: sc folded in agg, shift via zs*cstv in post) ----
    k_pk<1><<<PKBLK, 256, 0, stream>>>(h, U1, stats0, g0, p);
    k_agg<1><<<AGGBLK, 256, 0, stream>>>(rowptr, csr, p, hbf, c1, stats0, g0,
                                         z, zs);
    k_post<1, 1><<<POSTBLK, 256, 0, stream>>>(wl1, z, zs, W1, stats0, g0, bt0,
                                              b1, h, hbf, stats1);
    // ---- layer 2 (BN1) ----
    k_pk<1><<<PKBLK, 256, 0, stream>>>(h, U2, stats1, g1, p);
    k_agg<1><<<AGGBLK, 256, 0, stream>>>(rowptr, csr, p, hbf, c2, stats1, g1,
                                         z, zs);
    k_post<1, 0><<<POSTBLK, 256, 0, stream>>>(wl2, z, zs, W2, stats1, g1, bt1,
                                              b2, (float*)d_out, nullptr, nullptr);
}

// Round 5
// 365.583 us; speedup vs baseline: 5.6146x; 1.1782x over previous
//
#include <hip/hip_runtime.h>

#define NN 30000
#define NE 480000
#define BN_EPS 1e-5f
#define EBLK 1875     // NE/256 edge blocks
#define AGGBLK 7500   // wave per node
#define POSTBLK 938   // 2 node-groups x 16 nodes per block, 2 o-tiles per wave
#define PKBLK 469     // ceil(NN*4/256)

typedef __attribute__((ext_vector_type(8))) short bf16x8;
typedef __attribute__((ext_vector_type(4))) float f32x4;

// ---------------------------------------------------------------------------
// bf16 helpers (RNE pack, cheap unpack)
// ---------------------------------------------------------------------------
__device__ __forceinline__ unsigned short f2bf(float x) {
    unsigned int u = __float_as_uint(x);
    return (unsigned short)((u + 0x7fffu + ((u >> 16) & 1u)) >> 16);
}
__device__ __forceinline__ float bf2f(unsigned short h) {
    return __uint_as_float(((unsigned int)h) << 16);
}

// int64-vs-int32 detect: odd 32-bit words of int64 indices < 2^31 are all 0.
__device__ __forceinline__ int detect64(const unsigned int* __restrict__ ei) {
    unsigned int v = ei[1] | ei[3] | ei[5] | ei[7] |
                     ei[9] | ei[11] | ei[13] | ei[15];
    return v == 0u;
}
__device__ __forceinline__ int load_idx(const void* ei, int is64, int pos) {
    if (is64) return (int)((const long long*)ei)[pos];
    return ((const int*)ei)[pos];
}

// ---------------------------------------------------------------------------
// prep: x -> xbf (bf16), zero degi+cursor+stats, and pack W0..W2 into MFMA
// B-fragment order (bf16):
//   wb[layer][((ot*8 + kb)*64 + lane)*8 + e] = bf16( W[(m*64+o)*64+kk] )
//   with k = kb*32 + (lane>>4)*8 + e  (j index over 256 = m*64+kk),
//        o = ot*16 + (lane&15).
// Lane then loads its 8-elem fragment as one 16B vector load.
// ---------------------------------------------------------------------------
__global__ __launch_bounds__(256) void k_prep(const float* __restrict__ x,
                                              const float* __restrict__ W0,
                                              const float* __restrict__ W1,
                                              const float* __restrict__ W2,
                                              ushort* __restrict__ xbf,
                                              int4* __restrict__ zerobase,
                                              ushort* __restrict__ wb) {
    int t = blockIdx.x * 256 + threadIdx.x;
    if (t < 480000) {  // NN*64/4 ushort4s
        float4 v = reinterpret_cast<const float4*>(x)[t];
        ushort4 o;
        o.x = f2bf(v.x); o.y = f2bf(v.y); o.z = f2bf(v.z); o.w = f2bf(v.w);
        reinterpret_cast<ushort4*>(xbf)[t] = o;
    } else if (t < 480000 + 15064) {  // (2*NN ints + 256 floats)/4
        zerobase[t - 480000] = make_int4(0, 0, 0, 0);
    } else if (t < 480000 + 15064 + 49152) {
        int t2 = t - (480000 + 15064);
        int layer = t2 >> 14;
        int r = t2 & 16383;
        int ot = r >> 12;
        int kb = (r >> 9) & 7;
        int l = (r >> 3) & 63;
        int e = r & 7;
        int k = kb * 32 + (l >> 4) * 8 + e;
        int o = ot * 16 + (l & 15);
        int m = k >> 6;
        int kk = k & 63;
        const float* W = (layer == 0) ? W0 : (layer == 1) ? W1 : W2;
        wb[t2] = f2bf(W[(m * 64 + o) * 64 + kk]);
    }
}

// ---------------------------------------------------------------------------
// hist: dst-degree histogram (exactly NE threads)
// ---------------------------------------------------------------------------
__global__ __launch_bounds__(256) void k_hist(const void* __restrict__ ei,
                                              int* __restrict__ degi) {
    int e = blockIdx.x * 256 + threadIdx.x;
    int is64 = detect64((const unsigned int*)ei);
    int d = load_idx(ei, is64, NE + e);
    atomicAdd(&degi[d], 1);
}

// ---------------------------------------------------------------------------
// scan: ONE block, 1024 threads, 30 elems/thread -> exclusive rowptr.
// ---------------------------------------------------------------------------
__global__ __launch_bounds__(1024) void k_scan(const int* __restrict__ degi,
                                               int* __restrict__ rowptr) {
    __shared__ int sm[1024];
    const int PER = 30;
    int t = threadIdx.x;
    int base = t * PER;
    int loc[PER];
    int sum = 0;
#pragma unroll
    for (int i = 0; i < PER; ++i) {
        int idx = base + i;
        int d = (idx < NN) ? degi[idx] : 0;
        loc[i] = sum;
        sum += d;
    }
    sm[t] = sum;
    __syncthreads();
    for (int off = 1; off < 1024; off <<= 1) {
        int add = (t >= off) ? sm[t - off] : 0;
        __syncthreads();
        sm[t] += add;
        __syncthreads();
    }
    int tb = sm[t] - sum;
#pragma unroll
    for (int i = 0; i < PER; ++i) {
        int idx = base + i;
        if (idx < NN) rowptr[idx] = tb + loc[i];
    }
    if (t == 0) rowptr[NN] = NE;
}

// ---------------------------------------------------------------------------
// p-compute: p[n][m] = h[n,:] @ (U[m,:] * sc)  — one (node,head) per thread.
// ---------------------------------------------------------------------------
template <int FOLD>
__device__ __forceinline__ void dev_pk(const float* __restrict__ h,
                                       const float* __restrict__ U,
                                       const float* __restrict__ stats,
                                       const float* __restrict__ g,
                                       float* __restrict__ pout, int vb) {
    __shared__ float usc_s[4][64];
    int t = threadIdx.x;
    {
        int m = t >> 6, k = t & 63;
        float sc = 1.0f;
        if (FOLD) {
            const float invN = 1.0f / (float)NN;
            float mu = stats[k] * invN;
            float var = stats[64 + k] * invN - mu * mu;
            sc = rsqrtf(var + BN_EPS) * g[k];
        }
        usc_s[m][k] = U[m * 64 + k] * sc;
    }
    __syncthreads();
    int idx = vb * 256 + t;
    if (idx < NN * 4) {
        int n = idx >> 2, m = idx & 3;
        const float4* hn = reinterpret_cast<const float4*>(h) + (size_t)n * 16;
        const float* um = usc_s[m];
        float a = 0.0f;
#pragma unroll
        for (int j = 0; j < 16; ++j) {
            float4 hv = hn[j];
            a += hv.x * um[4 * j + 0] + hv.y * um[4 * j + 1] +
                 hv.z * um[4 * j + 2] + hv.w * um[4 * j + 3];
        }
        pout[idx] = a;
    }
}

template <int FOLD>
__global__ __launch_bounds__(256) void k_pk(const float* __restrict__ h,
                                            const float* __restrict__ U,
                                            const float* __restrict__ stats,
                                            const float* __restrict__ g,
                                            float* __restrict__ pout) {
    dev_pk<FOLD>(h, U, stats, g, pout, blockIdx.x);
}

// ---------------------------------------------------------------------------
// Fused: blocks 0..1874 scatter CSR; blocks 1875.. compute p0 = x@U0^T.
// ---------------------------------------------------------------------------
__global__ __launch_bounds__(256) void k_scatter_pk0(const void* __restrict__ ei,
                                                     const int* __restrict__ rowptr,
                                                     int* __restrict__ cursor,
                                                     int* __restrict__ csr,
                                                     const float* __restrict__ x,
                                                     const float* __restrict__ U0,
                                                     float* __restrict__ p) {
    if (blockIdx.x < EBLK) {
        int is64 = detect64((const unsigned int*)ei);
        int e = blockIdx.x * 256 + threadIdx.x;
        int s = load_idx(ei, is64, e);
        int d = load_idx(ei, is64, NE + e);
        int pos = rowptr[d] + atomicAdd(&cursor[d], 1);
        csr[pos] = s;
    } else {
        dev_pk<0>(x, U0, nullptr, nullptr, p, blockIdx.x - EBLK);
    }
}

// ---------------------------------------------------------------------------
// Aggregate: wave per dst node, lane = feature channel k. Gathers 128 B/edge
// of bf16 features (hbf, 3.84 MB, L2-resident). FOLD: scales the feature
// accumulators by BN sc[lane] so k_post is a pure GEMM + shift term.
//   z[n][m][k] = invD * sc[k] * [ selfattn_m*h_n[k] + sum_e attn_em*h_src[k] ]
//   zs[n][m]   = invD *        [ selfattn_m         + sum_e attn_em          ]
// ---------------------------------------------------------------------------
template <int FOLD>
__global__ __launch_bounds__(256) void k_agg(const int* __restrict__ rowptr,
                                             const int* __restrict__ csr,
                                             const float* __restrict__ p,
                                             const ushort* __restrict__ hbf,
                                             const float* __restrict__ cvec,
                                             const float* __restrict__ stats_in,
                                             const float* __restrict__ g,
                                             ushort* __restrict__ z,
                                             float* __restrict__ zs) {
    __shared__ float4 attn_s[4][64];
    __shared__ int src_s[4][64];
    int wid = threadIdx.x >> 6;
    int lane = threadIdx.x & 63;
    int n = blockIdx.x * 4 + wid;
    const float4* p4 = reinterpret_cast<const float4*>(p);

    float scl = 1.0f;
    if (FOLD) {
        const float invN = 1.0f / (float)NN;
        float mu = stats_in[lane] * invN;
        float var = stats_in[64 + lane] * invN - mu * mu;
        scl = rsqrtf(var + BN_EPS) * g[lane];
    }

    float4 cv = make_float4(cvec[0], cvec[1], cvec[2], cvec[3]);
    float smx = fmaxf(fmaxf(cv.x, cv.y), fmaxf(cv.z, cv.w));
    float se0 = __expf(cv.x - smx), se1 = __expf(cv.y - smx);
    float se2 = __expf(cv.z - smx), se3 = __expf(cv.w - smx);
    float sinv = 1.0f / (se0 + se1 + se2 + se3);
    float sl0 = se0 * sinv, sl1 = se1 * sinv, sl2 = se2 * sinv, sl3 = se3 * sinv;

    float4 pd = p4[n];
    float4 pdc = make_float4(pd.x + cv.x, pd.y + cv.y, pd.z + cv.z, pd.w + cv.w);
    float hs = bf2f(hbf[(unsigned)(n * 64 + lane)]);
    float acc0 = sl0 * hs, acc1 = sl1 * hs, acc2 = sl2 * hs, acc3 = sl3 * hs;
    float zt0 = sl0, zt1 = sl1, zt2 = sl2, zt3 = sl3;

    int start = rowptr[n];
    int end = rowptr[n + 1];
    for (int j = start; j < end; j += 64) {
        int chunk = end - j;
        if (chunk > 64) chunk = 64;
        if (lane < chunk) {
            int s = csr[j + lane];
            float4 q = p4[(unsigned)s];
            float l0 = pdc.x - q.x;
            float l1 = pdc.y - q.y;
            float l2 = pdc.z - q.z;
            float l3 = pdc.w - q.w;
            float mx = fmaxf(fmaxf(l0, l1), fmaxf(l2, l3));  // REQUIRED (R5 NaN)
            float e0 = __expf(l0 - mx);
            float e1 = __expf(l1 - mx);
            float e2 = __expf(l2 - mx);
            float e3 = __expf(l3 - mx);
            float inv = 1.0f / (e0 + e1 + e2 + e3);
            attn_s[wid][lane] = make_float4(e0 * inv, e1 * inv, e2 * inv, e3 * inv);
            src_s[wid][lane] = s;
        }
        int k = 0;
        for (; k + 4 <= chunk; k += 4) {
            float4 a0 = attn_s[wid][k];
            int s0 = src_s[wid][k];
            float4 a1 = attn_s[wid][k + 1];
            int s1 = src_s[wid][k + 1];
            float4 a2 = attn_s[wid][k + 2];
            int s2 = src_s[wid][k + 2];
            float4 a3 = attn_s[wid][k + 3];
            int s3 = src_s[wid][k + 3];
            float h0 = bf2f(hbf[(unsigned)(s0 * 64 + lane)]);
            float h1 = bf2f(hbf[(unsigned)(s1 * 64 + lane)]);
            float h2 = bf2f(hbf[(unsigned)(s2 * 64 + lane)]);
            float h3 = bf2f(hbf[(unsigned)(s3 * 64 + lane)]);
            acc0 += a0.x * h0 + a1.x * h1 + a2.x * h2 + a3.x * h3;
            acc1 += a0.y * h0 + a1.y * h1 + a2.y * h2 + a3.y * h3;
            acc2 += a0.z * h0 + a1.z * h1 + a2.z * h2 + a3.z * h3;
            acc3 += a0.w * h0 + a1.w * h1 + a2.w * h2 + a3.w * h3;
            zt0 += a0.x + a1.x + a2.x + a3.x;
            zt1 += a0.y + a1.y + a2.y + a3.y;
            zt2 += a0.z + a1.z + a2.z + a3.z;
            zt3 += a0.w + a1.w + a2.w + a3.w;
        }
        for (; k < chunk; ++k) {
            float4 a0 = attn_s[wid][k];
            int s0 = src_s[wid][k];
            float h0 = bf2f(hbf[(unsigned)(s0 * 64 + lane)]);
            acc0 += a0.x * h0;
            acc1 += a0.y * h0;
            acc2 += a0.z * h0;
            acc3 += a0.w * h0;
            zt0 += a0.x; zt1 += a0.y; zt2 += a0.z; zt3 += a0.w;
        }
    }

    float invD = 1.0f / (float)(end - start + 1);
    float s = invD * scl;
    unsigned base = (unsigned)n * 256 + lane;
    __builtin_nontemporal_store(f2bf(acc0 * s), &z[base]);
    __builtin_nontemporal_store(f2bf(acc1 * s), &z[base + 64]);
    __builtin_nontemporal_store(f2bf(acc2 * s), &z[base + 128]);
    __builtin_nontemporal_store(f2bf(acc3 * s), &z[base + 192]);
    if (lane == 0) {
        reinterpret_cast<float4*>(zs)[n] =
            make_float4(zt0 * invD, zt1 * invD, zt2 * invD, zt3 * invD);
    }
}

// ---------------------------------------------------------------------------
// Post (MFMA GEMM): out[n][o] = z[n][:] @ W[:][o]  (+ zs·cstv + b).
// Wave = 16 nodes x 2 o-tiles. A-frag: lane reads z[n0+(l&15)][kb*32+(l>>4)*8
// ..+8] as one 16B load. B-frag: packed bf16 (k_prep), lane-contiguous 16B.
// 8 x mfma_f32_16x16x32_bf16 per o-tile (K=256). D layout: row=(l>>4)*4+i,
// col=l&15 (HW-verified). Epilogue: shuffle-reduce stats, no barriers.
// ---------------------------------------------------------------------------
template <int FOLD, int STATS>
__global__ __launch_bounds__(256) void k_post(const ushort* __restrict__ wb,
                                              const ushort* __restrict__ z,
                                              const float* __restrict__ zsg,
                                              const float* __restrict__ W,
                                              const float* __restrict__ stats_in,
                                              const float* __restrict__ g,
                                              const float* __restrict__ bt,
                                              const float* __restrict__ bvec,
                                              float* __restrict__ hout,
                                              ushort* __restrict__ hbfout,
                                              float* __restrict__ stats_out) {
    __shared__ float cstv_s[256];
    int t = threadIdx.x;

    if (FOLD) {
        __shared__ float sh_s[64];
        if (t < 64) {
            const float invN = 1.0f / (float)NN;
            float mu = stats_in[t] * invN;
            float var = stats_in[64 + t] * invN - mu * mu;
            float sc = rsqrtf(var + BN_EPS) * g[t];
            sh_s[t] = bt[t] - mu * sc;
        }
        __syncthreads();
        float s = 0.0f;
        const float* wr = W + (size_t)t * 64;
#pragma unroll 8
        for (int k = 0; k < 64; ++k) s += sh_s[k] * wr[k];
        cstv_s[t] = s;
        __syncthreads();
    }

    int lane = t & 63;
    int wid = t >> 6;
    int ng = blockIdx.x * 2 + (wid >> 1);
    int n0 = ng * 16;
    bool valid = (n0 < NN);  // wave-uniform; NN%16==0 so valid waves are full

    int col = lane & 15;
    int grp = lane >> 4;

    // ---- A fragments: 8 k-blocks of z row (l&15), 16B vector loads ----
    int arow = n0 + col;
    if (arow > NN - 1) arow = NN - 1;
    const ushort* zr = z + (size_t)arow * 256 + grp * 8;
    bf16x8 a[8];
#pragma unroll
    for (int kb = 0; kb < 8; ++kb)
        a[kb] = *reinterpret_cast<const bf16x8*>(zr + kb * 32);

    // ---- 2 o-tiles per wave, 8 MFMA each ----
    int ota = (wid & 1);
    int otb = (wid & 1) + 2;
    const ushort* wba = wb + ((size_t)(ota * 8) * 64 + lane) * 8;
    const ushort* wbb = wb + ((size_t)(otb * 8) * 64 + lane) * 8;
    f32x4 acc0 = {0.0f, 0.0f, 0.0f, 0.0f};
    f32x4 acc1 = {0.0f, 0.0f, 0.0f, 0.0f};
#pragma unroll
    for (int kb = 0; kb < 8; ++kb) {
        bf16x8 b0 = *reinterpret_cast<const bf16x8*>(wba + (size_t)kb * 512);
        bf16x8 b1 = *reinterpret_cast<const bf16x8*>(wbb + (size_t)kb * 512);
        acc0 = __builtin_amdgcn_mfma_f32_16x16x32_bf16(a[kb], b0, acc0, 0, 0, 0);
        acc1 = __builtin_amdgcn_mfma_f32_16x16x32_bf16(a[kb], b1, acc1, 0, 0, 0);
    }

    // ---- epilogue (no barriers; guarded by wave-uniform valid) ----
    if (valid) {
        int oa = ota * 16 + col;
        int ob = otb * 16 + col;
        float4 zsv[4];
        if (FOLD) {
#pragma unroll
            for (int i = 0; i < 4; ++i)
                zsv[i] = reinterpret_cast<const float4*>(zsg)[n0 + grp * 4 + i];
        }
        float ba = bvec[oa];
        float bb = bvec[ob];
        float lsa = 0.0f, lqa = 0.0f, lsb = 0.0f, lqb = 0.0f;
#pragma unroll
        for (int i = 0; i < 4; ++i) {
            int n = n0 + grp * 4 + i;
            float va = acc0[i] + ba;
            float vb = acc1[i] + bb;
            if (FOLD) {
                va += zsv[i].x * cstv_s[oa] + zsv[i].y * cstv_s[64 + oa] +
                      zsv[i].z * cstv_s[128 + oa] + zsv[i].w * cstv_s[192 + oa];
                vb += zsv[i].x * cstv_s[ob] + zsv[i].y * cstv_s[64 + ob] +
                      zsv[i].z * cstv_s[128 + ob] + zsv[i].w * cstv_s[192 + ob];
            }
            if (STATS) {
                va = fmaxf(va, 0.0f);
                vb = fmaxf(vb, 0.0f);
                hout[(size_t)n * 64 + oa] = va;
                hout[(size_t)n * 64 + ob] = vb;
                hbfout[(size_t)n * 64 + oa] = f2bf(va);
                hbfout[(size_t)n * 64 + ob] = f2bf(vb);
                lsa += va; lqa += va * va;
                lsb += vb; lqb += vb * vb;
            } else {
                hout[(size_t)n * 64 + oa] = va;
                hout[(size_t)n * 64 + ob] = vb;
            }
        }
        if (STATS) {
            lsa += __shfl_xor(lsa, 16, 64); lsa += __shfl_xor(lsa, 32, 64);
            lqa += __shfl_xor(lqa, 16, 64); lqa += __shfl_xor(lqa, 32, 64);
            lsb += __shfl_xor(lsb, 16, 64); lsb += __shfl_xor(lsb, 32, 64);
            lqb += __shfl_xor(lqb, 16, 64); lqb += __shfl_xor(lqb, 32, 64);
            if (lane < 16) {
                atomicAdd(&stats_out[ota * 16 + lane], lsa);
                atomicAdd(&stats_out[64 + ota * 16 + lane], lqa);
                atomicAdd(&stats_out[otb * 16 + lane], lsb);
                atomicAdd(&stats_out[64 + otb * 16 + lane], lqb);
            }
        }
    }
}

extern "C" void kernel_launch(void* const* d_in, const int* in_sizes, int n_in,
                              void* d_out, int out_size, void* d_ws, size_t ws_size,
                              hipStream_t stream) {
    const float* x = (const float*)d_in[0];
    const void* ei = d_in[1];
    const float* W0 = (const float*)d_in[2];
    const float* U0 = (const float*)d_in[3];
    const float* c0 = (const float*)d_in[4];
    const float* b0 = (const float*)d_in[5];
    const float* g0 = (const float*)d_in[6];
    const float* bt0 = (const float*)d_in[7];
    const float* W1 = (const float*)d_in[8];
    const float* U1 = (const float*)d_in[9];
    const float* c1 = (const float*)d_in[10];
    const float* b1 = (const float*)d_in[11];
    const float* g1 = (const float*)d_in[12];
    const float* bt1 = (const float*)d_in[13];
    const float* W2 = (const float*)d_in[14];
    const float* U2 = (const float*)d_in[15];
    const float* c2 = (const float*)d_in[16];
    const float* b2 = (const float*)d_in[17];

    // workspace layout — every segment a multiple of 16 B
    ushort* xbf = (ushort*)d_ws;                      // NN*64
    ushort* hbf = xbf + (size_t)NN * 64;              // NN*64
    ushort* z = hbf + (size_t)NN * 64;                // NN*256 (15.36 MB)
    float* zs = (float*)(z + (size_t)NN * 256);       // NN*4
    float* h = zs + (size_t)NN * 4;                   // NN*64
    float* p = h + (size_t)NN * 64;                   // NN*4
    int* degi = (int*)(p + (size_t)NN * 4);           // NN   } zeroed as one
    int* cursor = degi + NN;                          // NN   } int4 region
    float* stats01 = (float*)(cursor + NN);           // 256  } (15064 int4)
    int* rowptr = (int*)(stats01 + 256);              // NN+4 (padded for align)
    int* csr = rowptr + NN + 4;                       // NE
    ushort* wb = (ushort*)(csr + NE);                 // 3*16384 bf16
    float* stats0 = stats01;
    float* stats1 = stats01 + 128;

    const int prepBlocks = (480000 + 15064 + 49152 + 255) / 256;  // 2126

    // 12 dispatches
    k_prep<<<prepBlocks, 256, 0, stream>>>(x, W0, W1, W2, xbf, (int4*)degi, wb);
    k_hist<<<EBLK, 256, 0, stream>>>(ei, degi);
    k_scan<<<1, 1024, 0, stream>>>(degi, rowptr);
    k_scatter_pk0<<<EBLK + PKBLK, 256, 0, stream>>>(ei, rowptr, cursor, csr,
                                                    x, U0, p);

    // ---- layer 0 (no BN in front) ----
    k_agg<0><<<AGGBLK, 256, 0, stream>>>(rowptr, csr, p, xbf, c0, nullptr,
                                         nullptr, z, zs);
    k_post<0, 1><<<POSTBLK, 256, 0, stream>>>(wb, z, zs, W0, nullptr, nullptr,
                                              nullptr, b0, h, hbf, stats0);
    // ---- layer 1 (BN0: sc folded in agg, shift via zs*cstv in post) ----
    k_pk<1><<<PKBLK, 256, 0, stream>>>(h, U1, stats0, g0, p);
    k_agg<1><<<AGGBLK, 256, 0, stream>>>(rowptr, csr, p, hbf, c1, stats0, g0,
                                         z, zs);
    k_post<1, 1><<<POSTBLK, 256, 0, stream>>>(wb + 16384, z, zs, W1, stats0, g0,
                                              bt0, b1, h, hbf, stats1);
    // ---- layer 2 (BN1) ----
    k_pk<1><<<PKBLK, 256, 0, stream>>>(h, U2, stats1, g1, p);
    k_agg<1><<<AGGBLK, 256, 0, stream>>>(rowptr, csr, p, hbf, c2, stats1, g1,
                                         z, zs);
    k_post<1, 0><<<POSTBLK, 256, 0, stream>>>(wb + 32768, z, zs, W2, stats1, g1,
                                              bt1, b2, (float*)d_out, nullptr,
                                              nullptr);
}

// Round 6
// 311.402 us; speedup vs baseline: 6.5915x; 1.1740x over previous
//
#include <hip/hip_runtime.h>

#define NN 30000
#define NE 480000
#define BN_EPS 1e-5f
#define EBLK 1875     // NE/256 edge blocks
#define FBLK 1875     // fused blocks: 16 nodes each (1024 thr = 16 waves)
#define PKBLK 469     // ceil(NN*4/256)

typedef __attribute__((ext_vector_type(8))) short bf16x8;
typedef __attribute__((ext_vector_type(4))) float f32x4;

// ---------------------------------------------------------------------------
// bf16 helpers (RNE pack, cheap unpack)
// ---------------------------------------------------------------------------
__device__ __forceinline__ unsigned short f2bf(float x) {
    unsigned int u = __float_as_uint(x);
    return (unsigned short)((u + 0x7fffu + ((u >> 16) & 1u)) >> 16);
}
__device__ __forceinline__ float bf2f(unsigned short h) {
    return __uint_as_float(((unsigned int)h) << 16);
}

// int64-vs-int32 detect: odd 32-bit words of int64 indices < 2^31 are all 0.
__device__ __forceinline__ int detect64(const unsigned int* __restrict__ ei) {
    unsigned int v = ei[1] | ei[3] | ei[5] | ei[7] |
                     ei[9] | ei[11] | ei[13] | ei[15];
    return v == 0u;
}
__device__ __forceinline__ int load_idx(const void* ei, int is64, int pos) {
    if (is64) return (int)((const long long*)ei)[pos];
    return ((const int*)ei)[pos];
}

// ---------------------------------------------------------------------------
// prep: x -> xbf (bf16), zero degi+cursor+stats, pack W0..W2 into MFMA
// B-fragment order (bf16):
//   wb[layer][((ot*8 + kb)*64 + lane)*8 + e] = bf16( W[(m*64+o)*64+kk] )
//   k = kb*32 + (lane>>4)*8 + e,  o = ot*16 + (lane&15),  m=k>>6, kk=k&63.
// ---------------------------------------------------------------------------
__global__ __launch_bounds__(256) void k_prep(const float* __restrict__ x,
                                              const float* __restrict__ W0,
                                              const float* __restrict__ W1,
                                              const float* __restrict__ W2,
                                              ushort* __restrict__ xbf,
                                              int4* __restrict__ zerobase,
                                              ushort* __restrict__ wb) {
    int t = blockIdx.x * 256 + threadIdx.x;
    if (t < 480000) {  // NN*64/4 ushort4s
        float4 v = reinterpret_cast<const float4*>(x)[t];
        ushort4 o;
        o.x = f2bf(v.x); o.y = f2bf(v.y); o.z = f2bf(v.z); o.w = f2bf(v.w);
        reinterpret_cast<ushort4*>(xbf)[t] = o;
    } else if (t < 480000 + 15064) {  // (2*NN ints + 256 floats)/4
        zerobase[t - 480000] = make_int4(0, 0, 0, 0);
    } else if (t < 480000 + 15064 + 49152) {
        int t2 = t - (480000 + 15064);
        int layer = t2 >> 14;
        int r = t2 & 16383;
        int ot = r >> 12;
        int kb = (r >> 9) & 7;
        int l = (r >> 3) & 63;
        int e = r & 7;
        int k = kb * 32 + (l >> 4) * 8 + e;
        int o = ot * 16 + (l & 15);
        int m = k >> 6;
        int kk = k & 63;
        const float* W = (layer == 0) ? W0 : (layer == 1) ? W1 : W2;
        wb[t2] = f2bf(W[(m * 64 + o) * 64 + kk]);
    }
}

// ---------------------------------------------------------------------------
// hist: dst-degree histogram (exactly NE threads)
// ---------------------------------------------------------------------------
__global__ __launch_bounds__(256) void k_hist(const void* __restrict__ ei,
                                              int* __restrict__ degi) {
    int e = blockIdx.x * 256 + threadIdx.x;
    int is64 = detect64((const unsigned int*)ei);
    int d = load_idx(ei, is64, NE + e);
    atomicAdd(&degi[d], 1);
}

// ---------------------------------------------------------------------------
// scan: ONE block, 1024 threads, 30 elems/thread -> exclusive rowptr.
// ---------------------------------------------------------------------------
__global__ __launch_bounds__(1024) void k_scan(const int* __restrict__ degi,
                                               int* __restrict__ rowptr) {
    __shared__ int sm[1024];
    const int PER = 30;
    int t = threadIdx.x;
    int base = t * PER;
    int loc[PER];
    int sum = 0;
#pragma unroll
    for (int i = 0; i < PER; ++i) {
        int idx = base + i;
        int d = (idx < NN) ? degi[idx] : 0;
        loc[i] = sum;
        sum += d;
    }
    sm[t] = sum;
    __syncthreads();
    for (int off = 1; off < 1024; off <<= 1) {
        int add = (t >= off) ? sm[t - off] : 0;
        __syncthreads();
        sm[t] += add;
        __syncthreads();
    }
    int tb = sm[t] - sum;
#pragma unroll
    for (int i = 0; i < PER; ++i) {
        int idx = base + i;
        if (idx < NN) rowptr[idx] = tb + loc[i];
    }
    if (t == 0) rowptr[NN] = NE;
}

// ---------------------------------------------------------------------------
// p-compute: p[n][m] = h[n,:] @ (U[m,:] * sc). FOLD block 0 additionally
// produces cstv[o2] = sum_k sh[k]*W[o2*64+k] for the next fused kernel.
// ---------------------------------------------------------------------------
template <int FOLD>
__device__ __forceinline__ void dev_pk(const float* __restrict__ h,
                                       const float* __restrict__ U,
                                       const float* __restrict__ stats,
                                       const float* __restrict__ g,
                                       float* __restrict__ pout, int vb) {
    __shared__ float usc_s[4][64];
    int t = threadIdx.x;
    {
        int m = t >> 6, k = t & 63;
        float sc = 1.0f;
        if (FOLD) {
            const float invN = 1.0f / (float)NN;
            float mu = stats[k] * invN;
            float var = stats[64 + k] * invN - mu * mu;
            sc = rsqrtf(var + BN_EPS) * g[k];
        }
        usc_s[m][k] = U[m * 64 + k] * sc;
    }
    __syncthreads();
    int idx = vb * 256 + t;
    if (idx < NN * 4) {
        int n = idx >> 2, m = idx & 3;
        const float4* hn = reinterpret_cast<const float4*>(h) + (size_t)n * 16;
        const float* um = usc_s[m];
        float a = 0.0f;
#pragma unroll
        for (int j = 0; j < 16; ++j) {
            float4 hv = hn[j];
            a += hv.x * um[4 * j + 0] + hv.y * um[4 * j + 1] +
                 hv.z * um[4 * j + 2] + hv.w * um[4 * j + 3];
        }
        pout[idx] = a;
    }
}

template <int FOLD>
__global__ __launch_bounds__(256) void k_pk(const float* __restrict__ h,
                                            const float* __restrict__ U,
                                            const float* __restrict__ stats,
                                            const float* __restrict__ g,
                                            const float* __restrict__ W,
                                            const float* __restrict__ bt,
                                            float* __restrict__ pout,
                                            float* __restrict__ cstv_out) {
    dev_pk<FOLD>(h, U, stats, g, pout, blockIdx.x);
    if (FOLD && blockIdx.x == 0) {
        int t = threadIdx.x;
        const float invN = 1.0f / (float)NN;
        float s = 0.0f;
        const float* wr = W + (size_t)t * 64;
#pragma unroll 8
        for (int k = 0; k < 64; ++k) {
            float mu = stats[k] * invN;
            float var = stats[64 + k] * invN - mu * mu;
            float sc = rsqrtf(var + BN_EPS) * g[k];
            float sh = bt[k] - mu * sc;
            s += sh * wr[k];
        }
        cstv_out[t] = s;
    }
}

// ---------------------------------------------------------------------------
// Fused: blocks 0..1874 scatter CSR; blocks 1875.. compute p0 = x@U0^T.
// ---------------------------------------------------------------------------
__global__ __launch_bounds__(256) void k_scatter_pk0(const void* __restrict__ ei,
                                                     const int* __restrict__ rowptr,
                                                     int* __restrict__ cursor,
                                                     int* __restrict__ csr,
                                                     const float* __restrict__ x,
                                                     const float* __restrict__ U0,
                                                     float* __restrict__ p) {
    if (blockIdx.x < EBLK) {
        int is64 = detect64((const unsigned int*)ei);
        int e = blockIdx.x * 256 + threadIdx.x;
        int s = load_idx(ei, is64, e);
        int d = load_idx(ei, is64, NE + e);
        int pos = rowptr[d] + atomicAdd(&cursor[d], 1);
        csr[pos] = s;
    } else {
        dev_pk<0>(x, U0, nullptr, nullptr, p, blockIdx.x - EBLK);
    }
}

// ---------------------------------------------------------------------------
// FUSED aggregate + GEMM. 1024 threads = 16 waves = 16 nodes per block.
// Phase A (wave per node, lane = channel k): gather-aggregate into registers,
// scale by invD*sc, write bf16 z row to LDS (padded stride 264 ushorts) + zs.
// One __syncthreads. Phase B (waves 0..3, one 16-col o-tile each):
// A-frags via ds_read_b128 from zrow, B-frags from packed wb (L2-hot),
// 8 x mfma_f32_16x16x32_bf16, epilogue: + zs*cstv + b, relu, h/hbf stores,
// per-channel stats atomics. z never touches global memory.
// ---------------------------------------------------------------------------
template <int FOLD, int STATS>
__global__ __launch_bounds__(1024, 8) void k_fused(const int* __restrict__ rowptr,
                                                   const int* __restrict__ csr,
                                                   const float* __restrict__ p,
                                                   const ushort* __restrict__ hbf_in,
                                                   const float* __restrict__ cvec,
                                                   const float* __restrict__ stats_in,
                                                   const float* __restrict__ g,
                                                   const float* __restrict__ cstvg,
                                                   const ushort* __restrict__ wb,
                                                   const float* __restrict__ bvec,
                                                   float* __restrict__ hout,
                                                   ushort* __restrict__ hbfout,
                                                   float* __restrict__ stats_out) {
    __shared__ float4 attn_s[16][64];
    __shared__ int src_s[16][64];
    __shared__ ushort zrow[16][264];   // 528 B stride: 16B-aligned, bank-benign
    __shared__ float4 zs_s[16];
    __shared__ float cstv_s[256];

    int t = threadIdx.x;
    int wid = t >> 6;
    int lane = t & 63;

    if (FOLD && t < 256) cstv_s[t] = cstvg[t];

    // ---- phase A: aggregate node n (identical math to prior k_agg) ----
    int n = blockIdx.x * 16 + wid;
    const float4* p4 = reinterpret_cast<const float4*>(p);

    float scl = 1.0f;
    if (FOLD) {
        const float invN = 1.0f / (float)NN;
        float mu = stats_in[lane] * invN;
        float var = stats_in[64 + lane] * invN - mu * mu;
        scl = rsqrtf(var + BN_EPS) * g[lane];
    }

    float4 cv = make_float4(cvec[0], cvec[1], cvec[2], cvec[3]);
    float smx = fmaxf(fmaxf(cv.x, cv.y), fmaxf(cv.z, cv.w));
    float se0 = __expf(cv.x - smx), se1 = __expf(cv.y - smx);
    float se2 = __expf(cv.z - smx), se3 = __expf(cv.w - smx);
    float sinv = 1.0f / (se0 + se1 + se2 + se3);
    float sl0 = se0 * sinv, sl1 = se1 * sinv, sl2 = se2 * sinv, sl3 = se3 * sinv;

    float4 pd = p4[n];
    float4 pdc = make_float4(pd.x + cv.x, pd.y + cv.y, pd.z + cv.z, pd.w + cv.w);
    float hs = bf2f(hbf_in[(unsigned)(n * 64 + lane)]);
    float acc0 = sl0 * hs, acc1 = sl1 * hs, acc2 = sl2 * hs, acc3 = sl3 * hs;
    float zt0 = sl0, zt1 = sl1, zt2 = sl2, zt3 = sl3;

    int start = rowptr[n];
    int end = rowptr[n + 1];
    for (int j = start; j < end; j += 64) {
        int chunk = end - j;
        if (chunk > 64) chunk = 64;
        if (lane < chunk) {
            int s = csr[j + lane];
            float4 q = p4[(unsigned)s];
            float l0 = pdc.x - q.x;
            float l1 = pdc.y - q.y;
            float l2 = pdc.z - q.z;
            float l3 = pdc.w - q.w;
            float mx = fmaxf(fmaxf(l0, l1), fmaxf(l2, l3));  // REQUIRED (R5 NaN)
            float e0 = __expf(l0 - mx);
            float e1 = __expf(l1 - mx);
            float e2 = __expf(l2 - mx);
            float e3 = __expf(l3 - mx);
            float inv = 1.0f / (e0 + e1 + e2 + e3);
            attn_s[wid][lane] = make_float4(e0 * inv, e1 * inv, e2 * inv, e3 * inv);
            src_s[wid][lane] = s;
        }
        int k = 0;
        for (; k + 4 <= chunk; k += 4) {
            float4 a0 = attn_s[wid][k];
            int s0 = src_s[wid][k];
            float4 a1 = attn_s[wid][k + 1];
            int s1 = src_s[wid][k + 1];
            float4 a2 = attn_s[wid][k + 2];
            int s2 = src_s[wid][k + 2];
            float4 a3 = attn_s[wid][k + 3];
            int s3 = src_s[wid][k + 3];
            float h0 = bf2f(hbf_in[(unsigned)(s0 * 64 + lane)]);
            float h1 = bf2f(hbf_in[(unsigned)(s1 * 64 + lane)]);
            float h2 = bf2f(hbf_in[(unsigned)(s2 * 64 + lane)]);
            float h3 = bf2f(hbf_in[(unsigned)(s3 * 64 + lane)]);
            acc0 += a0.x * h0 + a1.x * h1 + a2.x * h2 + a3.x * h3;
            acc1 += a0.y * h0 + a1.y * h1 + a2.y * h2 + a3.y * h3;
            acc2 += a0.z * h0 + a1.z * h1 + a2.z * h2 + a3.z * h3;
            acc3 += a0.w * h0 + a1.w * h1 + a2.w * h2 + a3.w * h3;
            zt0 += a0.x + a1.x + a2.x + a3.x;
            zt1 += a0.y + a1.y + a2.y + a3.y;
            zt2 += a0.z + a1.z + a2.z + a3.z;
            zt3 += a0.w + a1.w + a2.w + a3.w;
        }
        for (; k < chunk; ++k) {
            float4 a0 = attn_s[wid][k];
            int s0 = src_s[wid][k];
            float h0 = bf2f(hbf_in[(unsigned)(s0 * 64 + lane)]);
            acc0 += a0.x * h0;
            acc1 += a0.y * h0;
            acc2 += a0.z * h0;
            acc3 += a0.w * h0;
            zt0 += a0.x; zt1 += a0.y; zt2 += a0.z; zt3 += a0.w;
        }
    }

    float invD = 1.0f / (float)(end - start + 1);
    float s = invD * scl;
    {
        ushort* zr = &zrow[wid][0];
        zr[lane]        = f2bf(acc0 * s);
        zr[64 + lane]   = f2bf(acc1 * s);
        zr[128 + lane]  = f2bf(acc2 * s);
        zr[192 + lane]  = f2bf(acc3 * s);
        if (lane == 0)
            zs_s[wid] = make_float4(zt0 * invD, zt1 * invD, zt2 * invD, zt3 * invD);
    }
    __syncthreads();

    // ---- phase B: waves 0..3, one o-tile each (same layout R5 verified) ----
    if (wid < 4) {
        int col = lane & 15;
        int grp = lane >> 4;
        int ot = wid;
        const ushort* zr = &zrow[col][grp * 8];
        const ushort* wbp = wb + ((size_t)(ot * 8) * 64 + lane) * 8;
        f32x4 acc = {0.0f, 0.0f, 0.0f, 0.0f};
#pragma unroll
        for (int kb = 0; kb < 8; ++kb) {
            bf16x8 a = *reinterpret_cast<const bf16x8*>(zr + kb * 32);
            bf16x8 b = *reinterpret_cast<const bf16x8*>(wbp + (size_t)kb * 512);
            acc = __builtin_amdgcn_mfma_f32_16x16x32_bf16(a, b, acc, 0, 0, 0);
        }

        int n0 = blockIdx.x * 16;
        int o = ot * 16 + col;
        float bval = bvec[o];
        float ls = 0.0f, lq = 0.0f;
#pragma unroll
        for (int i = 0; i < 4; ++i) {
            int nn = n0 + grp * 4 + i;
            float v = acc[i] + bval;
            if (FOLD) {
                float4 zv = zs_s[grp * 4 + i];
                v += zv.x * cstv_s[o] + zv.y * cstv_s[64 + o] +
                     zv.z * cstv_s[128 + o] + zv.w * cstv_s[192 + o];
            }
            if (STATS) {
                v = fmaxf(v, 0.0f);
                hout[(size_t)nn * 64 + o] = v;
                hbfout[(size_t)nn * 64 + o] = f2bf(v);
                ls += v;
                lq += v * v;
            } else {
                hout[(size_t)nn * 64 + o] = v;
            }
        }
        if (STATS) {
            ls += __shfl_xor(ls, 16, 64); ls += __shfl_xor(ls, 32, 64);
            lq += __shfl_xor(lq, 16, 64); lq += __shfl_xor(lq, 32, 64);
            if (lane < 16) {
                atomicAdd(&stats_out[o], ls);
                atomicAdd(&stats_out[64 + o], lq);
            }
        }
    }
}

extern "C" void kernel_launch(void* const* d_in, const int* in_sizes, int n_in,
                              void* d_out, int out_size, void* d_ws, size_t ws_size,
                              hipStream_t stream) {
    const float* x = (const float*)d_in[0];
    const void* ei = d_in[1];
    const float* W0 = (const float*)d_in[2];
    const float* U0 = (const float*)d_in[3];
    const float* c0 = (const float*)d_in[4];
    const float* b0 = (const float*)d_in[5];
    const float* g0 = (const float*)d_in[6];
    const float* bt0 = (const float*)d_in[7];
    const float* W1 = (const float*)d_in[8];
    const float* U1 = (const float*)d_in[9];
    const float* c1 = (const float*)d_in[10];
    const float* b1 = (const float*)d_in[11];
    const float* g1 = (const float*)d_in[12];
    const float* bt1 = (const float*)d_in[13];
    const float* W2 = (const float*)d_in[14];
    const float* U2 = (const float*)d_in[15];
    const float* c2 = (const float*)d_in[16];
    const float* b2 = (const float*)d_in[17];

    // workspace layout — every segment 16B-aligned
    ushort* xbf = (ushort*)d_ws;                      // NN*64 bf16
    ushort* hbfA = xbf + (size_t)NN * 64;             // NN*64 (double buffer A)
    ushort* hbfB = hbfA + (size_t)NN * 64;            // NN*64 (double buffer B)
    float* h = (float*)(hbfB + (size_t)NN * 64);      // NN*64 fp32
    float* p = h + (size_t)NN * 64;                   // NN*4
    float* cstv = p + (size_t)NN * 4;                 // 256
    int* degi = (int*)(cstv + 256);                   // NN   } zeroed as one
    int* cursor = degi + NN;                          // NN   } int4 region
    float* stats01 = (float*)(cursor + NN);           // 256  } (15064 int4)
    int* rowptr = (int*)(stats01 + 256);              // NN+4
    int* csr = rowptr + NN + 4;                       // NE
    ushort* wb = (ushort*)(csr + NE);                 // 3*16384 bf16
    float* stats0 = stats01;
    float* stats1 = stats01 + 128;

    const int prepBlocks = (480000 + 15064 + 49152 + 255) / 256;  // 2126

    // 9 dispatches
    k_prep<<<prepBlocks, 256, 0, stream>>>(x, W0, W1, W2, xbf, (int4*)degi, wb);
    k_hist<<<EBLK, 256, 0, stream>>>(ei, degi);
    k_scan<<<1, 1024, 0, stream>>>(degi, rowptr);
    k_scatter_pk0<<<EBLK + PKBLK, 256, 0, stream>>>(ei, rowptr, cursor, csr,
                                                    x, U0, p);

    // ---- layer 0: read xbf, write h + hbfA, stats0 ----
    k_fused<0, 1><<<FBLK, 1024, 0, stream>>>(rowptr, csr, p, xbf, c0,
                                             nullptr, nullptr, nullptr,
                                             wb, b0, h, hbfA, stats0);
    // ---- layer 1: BN0 fold; read hbfA, write h + hbfB, stats1 ----
    k_pk<1><<<PKBLK, 256, 0, stream>>>(h, U1, stats0, g0, W1, bt0, p, cstv);
    k_fused<1, 1><<<FBLK, 1024, 0, stream>>>(rowptr, csr, p, hbfA, c1,
                                             stats0, g0, cstv,
                                             wb + 16384, b1, h, hbfB, stats1);
    // ---- layer 2: BN1 fold; read hbfB, write d_out ----
    k_pk<1><<<PKBLK, 256, 0, stream>>>(h, U2, stats1, g1, W2, bt1, p, cstv);
    k_fused<1, 0><<<FBLK, 1024, 0, stream>>>(rowptr, csr, p, hbfB, c2,
                                             stats1, g1, cstv,
                                             wb + 32768, b2, (float*)d_out,
                                             nullptr, nullptr);
}